// Round 1
// baseline (2294.139 us; speedup 1.0000x reference)
//
#include <hip/hip_runtime.h>
#include <cstddef>

#define Bn 4
#define Sn 4096
#define Hn 2048
#define Dn 256
#define MR (Bn * Sn)   // 16384 rows
#define LD3 768        // q|k|v fused row stride

// ---------------------------------------------------------------------------
// Projection GEMM: qkv[M][768] = x[M][2048] @ [wq | wk | wv]
// 64x64 tile, BK=16, 4x4 register tile per thread, 256 threads.
// ---------------------------------------------------------------------------
__global__ __launch_bounds__(256)
void proj_kernel(const float* __restrict__ x, const float* __restrict__ wq,
                 const float* __restrict__ wk, const float* __restrict__ wv,
                 float* __restrict__ qkv) {
  __shared__ float As[16][64];   // [k][m] (transposed A tile)
  __shared__ float Bs[16][64];   // [k][n]
  const int tid = threadIdx.x;
  const int m0 = blockIdx.x * 64;
  const int n0 = blockIdx.y * 64;                 // 0..767
  const float* w = (n0 < 256) ? wq : ((n0 < 512) ? wk : wv);
  const int nc0 = n0 & 255;
  const int ty = tid >> 4, tx = tid & 15;
  const int arow = tid >> 2, ak = (tid & 3) << 2; // A tile load mapping
  const int bk = tid >> 4, bn = (tid & 15) << 2;  // B tile load mapping

  float acc[4][4];
#pragma unroll
  for (int i = 0; i < 4; ++i)
#pragma unroll
    for (int j = 0; j < 4; ++j) acc[i][j] = 0.0f;

  for (int k0 = 0; k0 < Hn; k0 += 16) {
    const float4 av = *(const float4*)(x + (size_t)(m0 + arow) * Hn + k0 + ak);
    const float4 bv = *(const float4*)(w + (size_t)(k0 + bk) * Dn + nc0 + bn);
    As[ak + 0][arow] = av.x;
    As[ak + 1][arow] = av.y;
    As[ak + 2][arow] = av.z;
    As[ak + 3][arow] = av.w;
    *(float4*)&Bs[bk][bn] = bv;
    __syncthreads();
#pragma unroll
    for (int kk = 0; kk < 16; ++kk) {
      const float4 a4 = *(const float4*)&As[kk][ty << 2];
      const float4 b4 = *(const float4*)&Bs[kk][tx << 2];
      const float a[4] = {a4.x, a4.y, a4.z, a4.w};
      const float b[4] = {b4.x, b4.y, b4.z, b4.w};
#pragma unroll
      for (int i = 0; i < 4; ++i)
#pragma unroll
        for (int j = 0; j < 4; ++j) acc[i][j] = fmaf(a[i], b[j], acc[i][j]);
    }
    __syncthreads();
  }
#pragma unroll
  for (int i = 0; i < 4; ++i) {
    const float4 v = make_float4(acc[i][0], acc[i][1], acc[i][2], acc[i][3]);
    *(float4*)(qkv + (size_t)(m0 + (ty << 2) + i) * LD3 + n0 + (tx << 2)) = v;
  }
}

// ---------------------------------------------------------------------------
// xPos rotary, in place on q (cols 0..255, *scale) and k (cols 256..511, /scale)
// one thread per (row, pair j). 16384 rows * 128 pairs.
// ---------------------------------------------------------------------------
__global__ __launch_bounds__(256)
void xpos_kernel(float* __restrict__ qkv) {
  const int g = blockIdx.x * 256 + threadIdx.x;
  const int row = g >> 7;      // 0..16383
  const int j = g & 127;       // pair index
  const float s = (float)(row & (Sn - 1));
  // inv_freq = 10000^(-j/128)
  const float invfreq = exp2f((float)j * (-13.287712379549449f / 128.0f));
  float sn, cs;
  sincosf(s * invfreq, &sn, &cs);
  // scale_vec[j] = (2j + 0.4*256)/(1.4*256); scale = sv^((s-2048)/512)
  const float sv = ((float)(2 * j) + 102.4f) * (1.0f / 358.4f);
  const float p = (s - 2048.0f) * (1.0f / 512.0f);
  const float sc = exp2f(p * log2f(sv));
  const float sci = 1.0f / sc;

  float* qp = qkv + (size_t)row * LD3 + (j << 1);
  const float q0 = qp[0], q1 = qp[1];
  qp[0] = (q0 * cs - q1 * sn) * sc;
  qp[1] = (q1 * cs + q0 * sn) * sc;

  float* kp = qp + 256;
  const float k0 = kp[0], k1 = kp[1];
  kp[0] = (k0 * cs - k1 * sn) * sci;
  kp[1] = (k1 * cs + k0 * sn) * sci;
}

// ---------------------------------------------------------------------------
// Retention: out[b][s][:] = sum_{t<=s} gamma^(s-t) (q_s . k_t) v_t
// One block per (s-tile of 64, batch). Causal loop over t-tiles.
// Phase A: scores via 4 d-chunks of 64 staged in LDS (XOR-swizzled rows).
// Phase B: P (transposed in LDS) @ V per 64-col chunk.
// ---------------------------------------------------------------------------
__global__ __launch_bounds__(256)
void ret_kernel(const float* __restrict__ qkv, float* __restrict__ out) {
  __shared__ float Qc[64 * 64];     // swizzled [r][d^c]
  __shared__ float KVc[64 * 64];    // K: swizzled; V: plain (phase B)
  __shared__ float Pt[64 * 68];     // [t][s], padded stride 68
  const int tid = threadIdx.x;
  const int st = blockIdx.x;        // s-tile 0..63
  const int b = blockIdx.y;
  const int s0 = st << 6;
  const int ty = tid >> 4, tx = tid & 15;
  const int rowbase = b << 12;      // b * 4096
  const float l2g = log2f(0.96875f);

  float4 acc[4][4];                 // [row i][col-chunk qq], 64 outputs/thread
#pragma unroll
  for (int i = 0; i < 4; ++i)
#pragma unroll
    for (int q = 0; q < 4; ++q) acc[i][q] = make_float4(0.f, 0.f, 0.f, 0.f);

  for (int tt = 0; tt <= st; ++tt) {
    const int t0 = tt << 6;
    float accA[4][4];
#pragma unroll
    for (int i = 0; i < 4; ++i)
#pragma unroll
      for (int j = 0; j < 4; ++j) accA[i][j] = 0.0f;

    // -------- phase A: scores over 4 d-chunks --------
    for (int dc = 0; dc < 4; ++dc) {
      __syncthreads();  // previous users of Qc/KVc done
#pragma unroll
      for (int it = 0; it < 4; ++it) {
        const int flat = it * 1024 + tid * 4;
        const int r = flat >> 6, d = flat & 63;
        const int c = ((r >> 2) & 7) << 2;  // XOR swizzle constant
        const float4 qv = *(const float4*)(qkv + (size_t)(rowbase + s0 + r) * LD3 + (dc << 6) + d);
        const float4 kv = *(const float4*)(qkv + (size_t)(rowbase + t0 + r) * LD3 + 256 + (dc << 6) + d);
        *(float4*)&Qc[(r << 6) + (d ^ c)] = qv;
        *(float4*)&KVc[(r << 6) + (d ^ c)] = kv;
      }
      __syncthreads();
      const int ca = (ty & 7) << 2;
      const int cb = (tx & 7) << 2;
      for (int kb = 0; kb < 64; kb += 4) {
        float4 av[4], bv[4];
#pragma unroll
        for (int i = 0; i < 4; ++i)
          av[i] = *(const float4*)&Qc[(((ty << 2) + i) << 6) + (kb ^ ca)];
#pragma unroll
        for (int j = 0; j < 4; ++j)
          bv[j] = *(const float4*)&KVc[(((tx << 2) + j) << 6) + (kb ^ cb)];
#pragma unroll
        for (int i = 0; i < 4; ++i)
#pragma unroll
          for (int j = 0; j < 4; ++j) {
            accA[i][j] = fmaf(av[i].x, bv[j].x, accA[i][j]);
            accA[i][j] = fmaf(av[i].y, bv[j].y, accA[i][j]);
            accA[i][j] = fmaf(av[i].z, bv[j].z, accA[i][j]);
            accA[i][j] = fmaf(av[i].w, bv[j].w, accA[i][j]);
          }
      }
    }

    // -------- decay + write P (transposed) --------
#pragma unroll
    for (int i = 0; i < 4; ++i)
#pragma unroll
      for (int j = 0; j < 4; ++j) {
        const int sg = s0 + (ty << 2) + i;
        const int tg = t0 + (tx << 2) + j;
        const int dd = sg - tg;
        const float wgt = (dd >= 0) ? exp2f((float)dd * l2g) : 0.0f;
        Pt[((tx << 2) + j) * 68 + (ty << 2) + i] = accA[i][j] * wgt;
      }
    __syncthreads();  // P ready; phase A fully done -> KVc reusable

    // -------- phase B: out += P @ V, per 64-column chunk --------
    for (int qq = 0; qq < 4; ++qq) {
#pragma unroll
      for (int it = 0; it < 4; ++it) {
        const int flat = it * 1024 + tid * 4;
        const int r = flat >> 6, d = flat & 63;
        const float4 vv = *(const float4*)(qkv + (size_t)(rowbase + t0 + r) * LD3 + 512 + (qq << 6) + d);
        *(float4*)&KVc[(r << 6) + d] = vv;   // plain layout
      }
      __syncthreads();
      for (int kk = 0; kk < 64; ++kk) {
        const float4 pa = *(const float4*)&Pt[kk * 68 + (ty << 2)];
        const float4 bb = *(const float4*)&KVc[(kk << 6) + (tx << 2)];
        const float a[4] = {pa.x, pa.y, pa.z, pa.w};
#pragma unroll
        for (int i = 0; i < 4; ++i) {
          acc[i][qq].x = fmaf(a[i], bb.x, acc[i][qq].x);
          acc[i][qq].y = fmaf(a[i], bb.y, acc[i][qq].y);
          acc[i][qq].z = fmaf(a[i], bb.z, acc[i][qq].z);
          acc[i][qq].w = fmaf(a[i], bb.w, acc[i][qq].w);
        }
      }
      __syncthreads();  // before next V chunk overwrites KVc
    }
  }

#pragma unroll
  for (int i = 0; i < 4; ++i)
#pragma unroll
    for (int qq = 0; qq < 4; ++qq)
      *(float4*)(out + (size_t)(rowbase + s0 + (ty << 2) + i) * Dn + (qq << 6) + (tx << 2)) = acc[i][qq];
}

// ---------------------------------------------------------------------------
extern "C" void kernel_launch(void* const* d_in, const int* in_sizes, int n_in,
                              void* d_out, int out_size, void* d_ws, size_t ws_size,
                              hipStream_t stream) {
  (void)in_sizes; (void)n_in; (void)out_size; (void)ws_size;
  const float* x  = (const float*)d_in[0];
  const float* wq = (const float*)d_in[1];
  const float* wk = (const float*)d_in[2];
  const float* wv = (const float*)d_in[3];
  float* out = (float*)d_out;
  float* qkv = (float*)d_ws;  // [16384][768] f32 = 50.3 MB scratch

  proj_kernel<<<dim3(MR / 64, LD3 / 64), 256, 0, stream>>>(x, wq, wk, wv, qkv);
  xpos_kernel<<<(MR * 128) / 256, 256, 0, stream>>>(qkv);
  ret_kernel<<<dim3(Sn / 64, Bn), 256, 0, stream>>>(qkv, out);
}

// Round 2
// 356.790 us; speedup vs baseline: 6.4299x; 6.4299x over previous
//
#include <hip/hip_runtime.h>
#include <cstddef>
#include <cstdint>

#define Bn 4
#define Sn 4096
#define Hn 2048
#define Dn 256

typedef float f32x16 __attribute__((ext_vector_type(16)));
typedef short bf16x8 __attribute__((ext_vector_type(8)));

#define AS3 __attribute__((address_space(3)))
#define AS1 __attribute__((address_space(1)))

__device__ __forceinline__ unsigned short f2bf(float f) {
  union { float f; unsigned int u; } a; a.f = f;
  unsigned int r = a.u + 0x7fffu + ((a.u >> 16) & 1u);
  return (unsigned short)(r >> 16);
}
__device__ __forceinline__ float bf2f(unsigned int b) {
  union { unsigned int u; float f; } a; a.u = b << 16;
  return a.f;
}

// ---------------------------------------------------------------------------
// wt[768][2048] bf16 = [wq|wk|wv]^T, k-chunk (8 elems) swizzled: c' = c ^ (n&7)
// ---------------------------------------------------------------------------
__global__ __launch_bounds__(256) void wt_build(const float* __restrict__ wq,
                                                const float* __restrict__ wk,
                                                const float* __restrict__ wv,
                                                unsigned short* __restrict__ wt) {
  __shared__ __align__(16) unsigned short T[64][72];
  const int tid = threadIdx.x;
  const int k0 = blockIdx.x * 64;  // 32
  const int n0 = blockIdx.y * 64;  // 12
  const float* w = (n0 < 256) ? wq : (n0 < 512 ? wk : wv);
  const int nc0 = n0 & 255;
#pragma unroll
  for (int it = 0; it < 2; ++it) {
    int flat = it * 256 + tid;
    int r = flat >> 3, c8 = flat & 7;
    const float* src = w + (size_t)(k0 + r) * 256 + nc0 + c8 * 8;
    float4 v0 = *(const float4*)src;
    float4 v1 = *(const float4*)(src + 4);
    T[c8 * 8 + 0][r] = f2bf(v0.x); T[c8 * 8 + 1][r] = f2bf(v0.y);
    T[c8 * 8 + 2][r] = f2bf(v0.z); T[c8 * 8 + 3][r] = f2bf(v0.w);
    T[c8 * 8 + 4][r] = f2bf(v1.x); T[c8 * 8 + 5][r] = f2bf(v1.y);
    T[c8 * 8 + 6][r] = f2bf(v1.z); T[c8 * 8 + 7][r] = f2bf(v1.w);
  }
  __syncthreads();
#pragma unroll
  for (int it = 0; it < 2; ++it) {
    int flat = it * 256 + tid;
    int nr = flat >> 3, kc8 = flat & 7;
    int n = n0 + nr;
    int kc_sw = kc8 ^ (n & 7);
    uint4 val = *(const uint4*)&T[nr][kc8 * 8];
    *(uint4*)((char*)wt + (size_t)n * 4096 + (size_t)k0 * 2 + kc_sw * 16) = val;
  }
}

// ---------------------------------------------------------------------------
// proj: qkv[16384][768] bf16 = x @ wt^T.  128x128 tile, BK=64, 4 waves (2x2),
// mfma 32x32x16.  B via global_load_lds (wt pre-swizzled); A reg-staged with
// fused f32->bf16 convert + write-side swizzle.
// K-half of qkv (cols 256..511) stored chunk-swizzled: c' = c ^ (m&7).
// ---------------------------------------------------------------------------
__global__ __launch_bounds__(256, 2) void proj_kernel(const float* __restrict__ x,
                                                      const unsigned short* __restrict__ wt,
                                                      unsigned short* __restrict__ qkv) {
  __shared__ __align__(16) unsigned short As[128 * 64];
  __shared__ __align__(16) unsigned short Bs[128 * 64];
  const int tid = threadIdx.x;
  const int lane = tid & 63;
  const int wid = tid >> 6;
  const int wr = wid >> 1, wc = wid & 1;
  const int m0 = blockIdx.x * 128;
  const int n0 = blockIdx.y * 128;
  const int l31 = lane & 31, lh = lane >> 5;

  f32x16 acc[2][2];
#pragma unroll
  for (int i = 0; i < 2; ++i)
#pragma unroll
    for (int j = 0; j < 2; ++j) acc[i][j] = 0.0f;

  for (int k0 = 0; k0 < Hn; k0 += 64) {
    // B tile -> LDS via async DMA (linear; source pre-swizzled)
    {
      AS3 char* ldsb = (AS3 char*)Bs;
#pragma unroll
      for (int i = 0; i < 4; ++i) {
        int ou = i * 4096 + wid * 1024;
        int o = ou + lane * 16;
        int row = o >> 7, col = o & 127;
        const char* src = (const char*)wt + (size_t)(n0 + row) * 4096 + k0 * 2 + col;
        __builtin_amdgcn_global_load_lds((const AS1 unsigned int*)src,
                                         (AS3 unsigned int*)(ldsb + ou), 16, 0, 0);
      }
    }
    // A tile: f32 load -> bf16 -> swizzled LDS write
#pragma unroll
    for (int i = 0; i < 4; ++i) {
      int o = i * 256 + tid;
      int row = o >> 3, c8 = o & 7;
      const float* src = x + (size_t)(m0 + row) * 2048 + k0 + c8 * 8;
      float4 v0 = *(const float4*)src;
      float4 v1 = *(const float4*)(src + 4);
      uint4 val;
      val.x = f2bf(v0.x) | ((unsigned int)f2bf(v0.y) << 16);
      val.y = f2bf(v0.z) | ((unsigned int)f2bf(v0.w) << 16);
      val.z = f2bf(v1.x) | ((unsigned int)f2bf(v1.y) << 16);
      val.w = f2bf(v1.z) | ((unsigned int)f2bf(v1.w) << 16);
      *(uint4*)((char*)As + row * 128 + ((c8 * 16) ^ ((row & 7) << 4))) = val;
    }
    __syncthreads();
#pragma unroll
    for (int kc = 0; kc < 4; ++kc) {
      const int kb = kc * 32 + lh * 16;
      bf16x8 a[2], b[2];
#pragma unroll
      for (int i = 0; i < 2; ++i) {
        int mr = wr * 64 + i * 32 + l31;
        a[i] = *(const bf16x8*)((const char*)As + mr * 128 + (kb ^ ((mr & 7) << 4)));
        int nr = wc * 64 + i * 32 + l31;
        b[i] = *(const bf16x8*)((const char*)Bs + nr * 128 + (kb ^ ((nr & 7) << 4)));
      }
#pragma unroll
      for (int i = 0; i < 2; ++i)
#pragma unroll
        for (int j = 0; j < 2; ++j)
          acc[i][j] = __builtin_amdgcn_mfma_f32_32x32x16_bf16(a[i], b[j], acc[i][j], 0, 0, 0);
    }
    __syncthreads();
  }
  const bool khalf = (n0 >= 256 && n0 < 512);
#pragma unroll
  for (int i = 0; i < 2; ++i)
#pragma unroll
    for (int j = 0; j < 2; ++j)
#pragma unroll
      for (int reg = 0; reg < 16; ++reg) {
        int m = m0 + wr * 64 + i * 32 + (reg & 3) + 8 * (reg >> 2) + 4 * lh;
        int n = n0 + wc * 64 + j * 32 + l31;
        if (khalf) n = 256 + ((n - 256) ^ ((m & 7) << 3));
        qkv[(size_t)m * 768 + n] = f2bf(acc[i][j][reg]);
      }
}

// ---------------------------------------------------------------------------
// xpos rotary, in place, bf16. q *= scale, k *= 1/scale. k-half swizzle-aware.
// ---------------------------------------------------------------------------
__global__ __launch_bounds__(256) void xpos_kernel(unsigned short* __restrict__ qkv) {
  const int g = blockIdx.x * 256 + threadIdx.x;  // 524288
  const int m = g >> 5;
  const int c = g & 31;
  const float s = (float)(m & (Sn - 1));
  unsigned short* qrow = qkv + (size_t)m * 768;
  const int csw = c ^ (m & 7);
  uint4 qv = *(uint4*)(qrow + c * 8);
  uint4 kv = *(uint4*)(qrow + 256 + csw * 8);
  unsigned int* qu = (unsigned int*)&qv;
  unsigned int* ku = (unsigned int*)&kv;
  const float pw = (s - 2048.0f) * (1.0f / 512.0f);
#pragma unroll
  for (int p = 0; p < 4; ++p) {
    const int jp = c * 4 + p;
    const float invf = exp2f((float)jp * (-13.287712379549449f / 128.0f));
    float sn, cs;
    sincosf(s * invf, &sn, &cs);
    const float sv = (2.0f * jp + 102.4f) * (1.0f / 358.4f);
    const float sc = exp2f(pw * log2f(sv));
    const float sci = 1.0f / sc;
    float q0 = bf2f(qu[p] & 0xffffu), q1 = bf2f(qu[p] >> 16);
    float k0 = bf2f(ku[p] & 0xffffu), k1 = bf2f(ku[p] >> 16);
    float q0r = (q0 * cs - q1 * sn) * sc;
    float q1r = (q1 * cs + q0 * sn) * sc;
    float k0r = (k0 * cs - k1 * sn) * sci;
    float k1r = (k1 * cs + k0 * sn) * sci;
    qu[p] = f2bf(q0r) | ((unsigned int)f2bf(q1r) << 16);
    ku[p] = f2bf(k0r) | ((unsigned int)f2bf(k1r) << 16);
  }
  *(uint4*)(qrow + c * 8) = qv;
  *(uint4*)(qrow + 256 + csw * 8) = kv;
}

// ---------------------------------------------------------------------------
// vt[b][d][t] = v[b][t][d]  (plain layout, 64x64 LDS tile transpose)
// ---------------------------------------------------------------------------
__global__ __launch_bounds__(256) void vt_build(const unsigned short* __restrict__ qkv,
                                                unsigned short* __restrict__ vt) {
  __shared__ __align__(16) unsigned short T[64][72];
  const int tid = threadIdx.x;
  const int t0 = blockIdx.x * 64;
  const int d0 = (blockIdx.y & 3) * 64;
  const int b = blockIdx.y >> 2;
  const unsigned short* src = qkv + (size_t)(b * Sn + t0) * 768 + 512 + d0;
#pragma unroll
  for (int it = 0; it < 2; ++it) {
    int flat = it * 256 + tid;
    int r = flat >> 3, c8 = flat & 7;
    uint4 v = *(const uint4*)(src + (size_t)r * 768 + c8 * 8);
    const unsigned short* e = (const unsigned short*)&v;
#pragma unroll
    for (int j = 0; j < 8; ++j) T[c8 * 8 + j][r] = e[j];
  }
  __syncthreads();
#pragma unroll
  for (int it = 0; it < 2; ++it) {
    int flat = it * 256 + tid;
    int dr = flat >> 3, tc8 = flat & 7;
    uint4 v = *(const uint4*)&T[dr][tc8 * 8];
    *(uint4*)(vt + (size_t)(b * 256 + d0 + dr) * 4096 + t0 + tc8 * 8) = v;
  }
}

// ---------------------------------------------------------------------------
// Retention: out[b][s][:] = sum_{t<=s} gamma^(s-t) (q_s.k_t) v_t
// Block = (b, 64-s tile), 4 waves = 2 s-groups x 2 t-phases.
// Swapped QK^T (mfma(K,Q)) -> score col = lane -> P in-register via
// cvt_pk_bf16 + permlane32_swap, then PV mfma. f32 accum, LDS phase-combine.
// ---------------------------------------------------------------------------
#define L2G -0.04580953603129484f
__global__ __launch_bounds__(256, 2) void ret_kernel(const unsigned short* __restrict__ qkv,
                                                     const unsigned short* __restrict__ vt,
                                                     float* __restrict__ out) {
  __shared__ __align__(16) char lds[65536];  // [phase][K 16KB] at ph*16384; V at 32768+ph*16384
  const int tid = threadIdx.x;
  const int lane = tid & 63;
  const int wid = tid >> 6;
  const int tw = wid & 1, sw = wid >> 1;
  const int l31 = lane & 31, lh = lane >> 5;
  const int st = blockIdx.x;
  const int b = blockIdx.y;
  const int s0w = st * 64 + sw * 32;
  const size_t qbase = (size_t)b * Sn;
  char* Kbuf = lds + tw * 16384;
  char* Vbuf = lds + 32768 + tw * 16384;
  const int pt = sw * 64 + lane;  // phase-local thread 0..127

  f32x16 acc[8];
#pragma unroll
  for (int i = 0; i < 8; ++i) acc[i] = 0.0f;

  const int iters = st + 1;  // tiles T = 2(st+1) of 32 t, 2 per iteration
  for (int it = 0; it < iters; ++it) {
    const int ti = 2 * it + tw;
    const int t0 = ti * 32;
    // ---- stage K (async DMA, linear; source swizzled in qkv) ----
    {
      AS3 char* kl = (AS3 char*)Kbuf;
#pragma unroll
      for (int i = 0; i < 8; ++i) {
        int ou = (sw * 8 + i) * 1024;
        int o = ou + lane * 16;
        int t = o >> 9, colB = o & 511;
        const char* src = (const char*)qkv + (qbase + t0 + t) * 1536 + 512 + colB;
        __builtin_amdgcn_global_load_lds((const AS1 unsigned int*)src,
                                         (AS3 unsigned int*)(kl + ou), 16, 0, 0);
      }
    }
    // ---- stage V (reg, write-side swizzle) ----
    {
      uint4 vv[8];
#pragma unroll
      for (int r = 0; r < 8; ++r) {
        int flat = r * 128 + pt;
        int d = flat >> 2, cc = flat & 3;
        vv[r] = *(const uint4*)((const char*)vt + ((size_t)(b * 256 + d) * 4096 + t0 + cc * 8) * 2);
      }
#pragma unroll
      for (int r = 0; r < 8; ++r) {
        int flat = r * 128 + pt;
        int d = flat >> 2, cc = flat & 3;
        *(uint4*)(Vbuf + d * 64 + ((cc * 16) ^ ((d & 3) << 4))) = vv[r];
      }
    }
    __syncthreads();
    // ---- QK^T (swapped): St[t][s], 32x32, K from LDS, Q from global ----
    f32x16 sacc = 0.0f;
#pragma unroll 4
    for (int dc = 0; dc < 16; ++dc) {
      const int kb = dc * 32 + lh * 16;
      bf16x8 kf = *(const bf16x8*)(Kbuf + l31 * 512 + (kb ^ ((l31 & 7) << 4)));
      bf16x8 qf = *(const bf16x8*)((const char*)qkv + (qbase + s0w + l31) * 1536 + kb);
      sacc = __builtin_amdgcn_mfma_f32_32x32x16_bf16(kf, qf, sacc, 0, 0, 0);
    }
    // ---- decay + pack bf16 pairs + half-swap -> in-register P fragments ----
    unsigned int P[8];
    {
      const int sg = s0w + l31;
#pragma unroll
      for (int k = 0; k < 8; ++k) {
        int r0 = 2 * k;
        int tg0 = t0 + (r0 & 3) + 8 * (r0 >> 2) + 4 * lh;
        int d0 = sg - tg0, d1 = d0 - 1;
        float w0 = (d0 < 0) ? 0.0f : exp2f((float)d0 * L2G);
        float w1 = (d1 < 0) ? 0.0f : exp2f((float)d1 * L2G);
        float f0 = sacc[r0] * w0, f1 = sacc[r0 + 1] * w1;
        unsigned int pk;
        asm("v_cvt_pk_bf16_f32 %0, %1, %2" : "=v"(pk) : "v"(f0), "v"(f1));
        P[k] = pk;
      }
      asm volatile("v_permlane32_swap_b32 %0, %1" : "+v"(P[0]), "+v"(P[2]));
      asm volatile("v_permlane32_swap_b32 %0, %1" : "+v"(P[1]), "+v"(P[3]));
      asm volatile("v_permlane32_swap_b32 %0, %1" : "+v"(P[4]), "+v"(P[6]));
      asm volatile("v_permlane32_swap_b32 %0, %1" : "+v"(P[5]), "+v"(P[7]));
    }
    // ---- PV: out[s][d] += P . V ----
#pragma unroll
    for (int kc = 0; kc < 2; ++kc) {
      uint4 pwp;
      pwp.x = P[kc * 4 + 0]; pwp.y = P[kc * 4 + 1];
      pwp.z = P[kc * 4 + 2]; pwp.w = P[kc * 4 + 3];
      bf16x8 pf = *(const bf16x8*)&pwp;
#pragma unroll
      for (int ng = 0; ng < 8; ++ng) {
        int d = ng * 32 + l31;
        bf16x8 vf = *(const bf16x8*)(Vbuf + d * 64 + (((kc * 32) + lh * 16) ^ ((d & 3) << 4)));
        acc[ng] = __builtin_amdgcn_mfma_f32_32x32x16_bf16(pf, vf, acc[ng], 0, 0, 0);
      }
    }
    __syncthreads();
  }
  // ---- combine t-phases via LDS and store ----
  if (tw == 1) {
    float* dst = (float*)(lds + sw * 32768);
#pragma unroll
    for (int ng = 0; ng < 8; ++ng)
#pragma unroll
      for (int reg = 0; reg < 16; ++reg) {
        int sl = (reg & 3) + 8 * (reg >> 2) + 4 * lh;
        int d = ng * 32 + l31;
        dst[sl * 256 + d] = acc[ng][reg];
      }
  }
  __syncthreads();
  if (tw == 0) {
    const float* prt = (const float*)(lds + sw * 32768);
#pragma unroll
    for (int ng = 0; ng < 8; ++ng)
#pragma unroll
      for (int reg = 0; reg < 16; ++reg) {
        int sl = (reg & 3) + 8 * (reg >> 2) + 4 * lh;
        int d = ng * 32 + l31;
        float v = acc[ng][reg] + prt[sl * 256 + d];
        out[((size_t)(b * Sn + st * 64 + sw * 32 + sl)) * 256 + d] = v;
      }
  }
}

// ---------------------------------------------------------------------------
extern "C" void kernel_launch(void* const* d_in, const int* in_sizes, int n_in,
                              void* d_out, int out_size, void* d_ws, size_t ws_size,
                              hipStream_t stream) {
  (void)in_sizes; (void)n_in; (void)out_size; (void)ws_size;
  const float* x  = (const float*)d_in[0];
  const float* wq = (const float*)d_in[1];
  const float* wk = (const float*)d_in[2];
  const float* wv = (const float*)d_in[3];
  float* out = (float*)d_out;
  char* ws = (char*)d_ws;
  unsigned short* vt  = (unsigned short*)(ws);              //  8,388,608 B
  unsigned short* wt  = (unsigned short*)(ws + 8388608);    //  3,145,728 B
  unsigned short* qkv = (unsigned short*)(ws + 11534336);   // 25,165,824 B

  wt_build<<<dim3(32, 12), 256, 0, stream>>>(wq, wk, wv, wt);
  proj_kernel<<<dim3(128, 6), 256, 0, stream>>>(x, wt, qkv);
  xpos_kernel<<<2048, 256, 0, stream>>>(qkv);
  vt_build<<<dim3(64, 16), 256, 0, stream>>>(qkv, vt);
  ret_kernel<<<dim3(64, 4), 256, 0, stream>>>(qkv, vt, out);
}

// Round 3
// 222.048 us; speedup vs baseline: 10.3317x; 1.6068x over previous
//
#include <hip/hip_runtime.h>
#include <cstddef>
#include <cstdint>

#define Bn 4
#define Sn 4096
#define Hn 2048
#define Dn 256

typedef float f32x16 __attribute__((ext_vector_type(16)));
typedef short bf16x8 __attribute__((ext_vector_type(8)));

#define AS3 __attribute__((address_space(3)))
#define AS1 __attribute__((address_space(1)))

// log2(0.96875) exact-ish; gamma^256
#define L2G -0.045803689613125f
#define GC 2.9526131e-4f

__device__ __forceinline__ unsigned short f2bf(float f) {
  union { float f; unsigned int u; } a; a.f = f;
  unsigned int r = a.u + 0x7fffu + ((a.u >> 16) & 1u);
  return (unsigned short)(r >> 16);
}
__device__ __forceinline__ float bf2f(unsigned int b) {
  union { unsigned int u; float f; } a; a.u = b << 16;
  return a.f;
}

// ---------------------------------------------------------------------------
// wt[768][2048] bf16 = [wq|wk|wv]^T, k-chunk (8 elems) swizzled: c' = c ^ (n&7)
// ---------------------------------------------------------------------------
__global__ __launch_bounds__(256) void wt_build(const float* __restrict__ wq,
                                                const float* __restrict__ wk,
                                                const float* __restrict__ wv,
                                                unsigned short* __restrict__ wt) {
  __shared__ __align__(16) unsigned short T[64][72];
  const int tid = threadIdx.x;
  const int k0 = blockIdx.x * 64;
  const int n0 = blockIdx.y * 64;
  const float* w = (n0 < 256) ? wq : (n0 < 512 ? wk : wv);
  const int nc0 = n0 & 255;
#pragma unroll
  for (int it = 0; it < 2; ++it) {
    int flat = it * 256 + tid;
    int r = flat >> 3, c8 = flat & 7;
    const float* src = w + (size_t)(k0 + r) * 256 + nc0 + c8 * 8;
    float4 v0 = *(const float4*)src;
    float4 v1 = *(const float4*)(src + 4);
    T[c8 * 8 + 0][r] = f2bf(v0.x); T[c8 * 8 + 1][r] = f2bf(v0.y);
    T[c8 * 8 + 2][r] = f2bf(v0.z); T[c8 * 8 + 3][r] = f2bf(v0.w);
    T[c8 * 8 + 4][r] = f2bf(v1.x); T[c8 * 8 + 5][r] = f2bf(v1.y);
    T[c8 * 8 + 6][r] = f2bf(v1.z); T[c8 * 8 + 7][r] = f2bf(v1.w);
  }
  __syncthreads();
#pragma unroll
  for (int it = 0; it < 2; ++it) {
    int flat = it * 256 + tid;
    int nr = flat >> 3, kc8 = flat & 7;
    int n = n0 + nr;
    int kc_sw = kc8 ^ (n & 7);
    uint4 val = *(const uint4*)&T[nr][kc8 * 8];
    *(uint4*)((char*)wt + (size_t)n * 4096 + (size_t)k0 * 2 + kc_sw * 16) = val;
  }
}

// ---------------------------------------------------------------------------
// proj: qkv[16384][768] bf16 = x @ wt^T. 128x128, BK=64, 4 waves, mfma 32x32x16.
// K-half of qkv stored chunk-swizzled: c8' = c8 ^ (m&7).
// ---------------------------------------------------------------------------
__global__ __launch_bounds__(256, 2) void proj_kernel(const float* __restrict__ x,
                                                      const unsigned short* __restrict__ wt,
                                                      unsigned short* __restrict__ qkv) {
  __shared__ __align__(16) unsigned short As[128 * 64];
  __shared__ __align__(16) unsigned short Bs[128 * 64];
  const int tid = threadIdx.x;
  const int lane = tid & 63;
  const int wid = tid >> 6;
  const int wr = wid >> 1, wc = wid & 1;
  const int m0 = blockIdx.x * 128;
  const int n0 = blockIdx.y * 128;
  const int l31 = lane & 31, lh = lane >> 5;

  f32x16 acc[2][2];
#pragma unroll
  for (int i = 0; i < 2; ++i)
#pragma unroll
    for (int j = 0; j < 2; ++j) acc[i][j] = 0.0f;

  for (int k0 = 0; k0 < Hn; k0 += 64) {
    {
      AS3 char* ldsb = (AS3 char*)Bs;
#pragma unroll
      for (int i = 0; i < 4; ++i) {
        int ou = i * 4096 + wid * 1024;
        int o = ou + lane * 16;
        int row = o >> 7, col = o & 127;
        const char* src = (const char*)wt + (size_t)(n0 + row) * 4096 + k0 * 2 + col;
        __builtin_amdgcn_global_load_lds((const AS1 unsigned int*)src,
                                         (AS3 unsigned int*)(ldsb + ou), 16, 0, 0);
      }
    }
#pragma unroll
    for (int i = 0; i < 4; ++i) {
      int o = i * 256 + tid;
      int row = o >> 3, c8 = o & 7;
      const float* src = x + (size_t)(m0 + row) * 2048 + k0 + c8 * 8;
      float4 v0 = *(const float4*)src;
      float4 v1 = *(const float4*)(src + 4);
      uint4 val;
      val.x = f2bf(v0.x) | ((unsigned int)f2bf(v0.y) << 16);
      val.y = f2bf(v0.z) | ((unsigned int)f2bf(v0.w) << 16);
      val.z = f2bf(v1.x) | ((unsigned int)f2bf(v1.y) << 16);
      val.w = f2bf(v1.z) | ((unsigned int)f2bf(v1.w) << 16);
      *(uint4*)((char*)As + row * 128 + ((c8 * 16) ^ ((row & 7) << 4))) = val;
    }
    __syncthreads();
#pragma unroll
    for (int kc = 0; kc < 4; ++kc) {
      const int kb = kc * 32 + lh * 16;
      bf16x8 a[2], b[2];
#pragma unroll
      for (int i = 0; i < 2; ++i) {
        int mr = wr * 64 + i * 32 + l31;
        a[i] = *(const bf16x8*)((const char*)As + mr * 128 + (kb ^ ((mr & 7) << 4)));
        int nr = wc * 64 + i * 32 + l31;
        b[i] = *(const bf16x8*)((const char*)Bs + nr * 128 + (kb ^ ((nr & 7) << 4)));
      }
#pragma unroll
      for (int i = 0; i < 2; ++i)
#pragma unroll
        for (int j = 0; j < 2; ++j)
          acc[i][j] = __builtin_amdgcn_mfma_f32_32x32x16_bf16(a[i], b[j], acc[i][j], 0, 0, 0);
    }
    __syncthreads();
  }
  const bool khalf = (n0 >= 256 && n0 < 512);
#pragma unroll
  for (int i = 0; i < 2; ++i)
#pragma unroll
    for (int j = 0; j < 2; ++j)
#pragma unroll
      for (int reg = 0; reg < 16; ++reg) {
        int m = m0 + wr * 64 + i * 32 + (reg & 3) + 8 * (reg >> 2) + 4 * lh;
        int n = n0 + wc * 64 + j * 32 + l31;
        if (khalf) n = 256 + ((n - 256) ^ ((m & 7) << 3));
        qkv[(size_t)m * 768 + n] = f2bf(acc[i][j][reg]);
      }
}

// ---------------------------------------------------------------------------
// xpos rotary + chunk decay folding, in place on bf16 qkv.
// q *= sc * gamma^tau ; k *= 1/(sc * gamma^tau), tau = s mod 256.
// ---------------------------------------------------------------------------
__global__ __launch_bounds__(256) void xpos_kernel(unsigned short* __restrict__ qkv) {
  const int g = blockIdx.x * 256 + threadIdx.x;
  const int m = g >> 5;
  const int c = g & 31;
  const float s = (float)(m & (Sn - 1));
  unsigned short* qrow = qkv + (size_t)m * 768;
  const int csw = c ^ (m & 7);
  uint4 qv = *(uint4*)(qrow + c * 8);
  uint4 kv = *(uint4*)(qrow + 256 + csw * 8);
  unsigned int* qu = (unsigned int*)&qv;
  unsigned int* ku = (unsigned int*)&kv;
  const float pw = (s - 2048.0f) * (1.0f / 512.0f);
  const float gp = exp2f((float)(m & 255) * L2G);  // gamma^tau
#pragma unroll
  for (int p = 0; p < 4; ++p) {
    const int jp = c * 4 + p;
    const float invf = exp2f((float)jp * (-13.287712379549449f / 128.0f));
    float sn, cs;
    sincosf(s * invf, &sn, &cs);
    const float sv = (2.0f * jp + 102.4f) * (1.0f / 358.4f);
    const float scq = exp2f(pw * log2f(sv)) * gp;
    const float sci = 1.0f / scq;
    float q0 = bf2f(qu[p] & 0xffffu), q1 = bf2f(qu[p] >> 16);
    float k0 = bf2f(ku[p] & 0xffffu), k1 = bf2f(ku[p] >> 16);
    float q0r = (q0 * cs - q1 * sn) * scq;
    float q1r = (q1 * cs + q0 * sn) * scq;
    float k0r = (k0 * cs - k1 * sn) * sci;
    float k1r = (k1 * cs + k0 * sn) * sci;
    qu[p] = f2bf(q0r) | ((unsigned int)f2bf(q1r) << 16);
    ku[p] = f2bf(k0r) | ((unsigned int)f2bf(k1r) << 16);
  }
  *(uint4*)(qrow + c * 8) = qv;
  *(uint4*)(qrow + 256 + csw * 8) = kv;
}

// ---------------------------------------------------------------------------
// kt[b][d][t] = k~[b][t][d] (deswizzled), vt[b][d][t] = v[b][t][d]
// ---------------------------------------------------------------------------
__global__ __launch_bounds__(256) void kvt_build(const unsigned short* __restrict__ qkv,
                                                 unsigned short* __restrict__ kt,
                                                 unsigned short* __restrict__ vt) {
  __shared__ __align__(16) unsigned short Tk[64][72];
  __shared__ __align__(16) unsigned short Tv[64][72];
  const int tid = threadIdx.x;
  const int t0 = blockIdx.x * 64;
  const int d0 = blockIdx.y * 64;
  const int b = blockIdx.z;
  const size_t rowb = ((size_t)b * Sn + t0) * 1536;
#pragma unroll
  for (int it = 0; it < 2; ++it) {
    int flat = it * 256 + tid;
    int r = flat >> 3, c8 = flat & 7;
    int kc = (d0 >> 3) + c8;
    int kcs = kc ^ (r & 7);
    uint4 kvv = *(const uint4*)((const char*)qkv + rowb + (size_t)r * 1536 + 512 + kcs * 16);
    uint4 vvv = *(const uint4*)((const char*)qkv + rowb + (size_t)r * 1536 + 1024 + (size_t)(d0 + c8 * 8) * 2);
    const unsigned short* ke = (const unsigned short*)&kvv;
    const unsigned short* ve = (const unsigned short*)&vvv;
#pragma unroll
    for (int e = 0; e < 8; ++e) { Tk[c8 * 8 + e][r] = ke[e]; Tv[c8 * 8 + e][r] = ve[e]; }
  }
  __syncthreads();
#pragma unroll
  for (int it = 0; it < 2; ++it) {
    int flat = it * 256 + tid;
    int dr = flat >> 3, tc8 = flat & 7;
    *(uint4*)(kt + (size_t)(b * 256 + d0 + dr) * 4096 + t0 + tc8 * 8) = *(const uint4*)&Tk[dr][tc8 * 8];
    *(uint4*)(vt + (size_t)(b * 256 + d0 + dr) * 4096 + t0 + tc8 * 8) = *(const uint4*)&Tv[dr][tc8 * 8];
  }
}

// ---------------------------------------------------------------------------
// mbuild: Mt[b][j][d2][d1] = sum_t V[t][d2] * K~[t][d1]  (= M^T), bf16 out.
// grid (16 chunks, 4 quadrants, 4 b); 4 waves = 2x2 of 64x64.
// ---------------------------------------------------------------------------
__global__ __launch_bounds__(256) void mbuild_kernel(const unsigned short* __restrict__ kt,
                                                     const unsigned short* __restrict__ vt,
                                                     unsigned short* __restrict__ mt) {
  const int tid = threadIdx.x;
  const int lane = tid & 63;
  const int wid = tid >> 6;
  const int l31 = lane & 31, lh = lane >> 5;
  const int jc = blockIdx.x;
  const int quad = blockIdx.y;
  const int b = blockIdx.z;
  const int d2w = ((quad >> 1) * 2 + (wid >> 1)) * 64;
  const int d1w = ((quad & 1) * 2 + (wid & 1)) * 64;
  const size_t tb = (size_t)jc * 256;

  f32x16 acc[2][2];
#pragma unroll
  for (int i = 0; i < 2; ++i)
#pragma unroll
    for (int j = 0; j < 2; ++j) acc[i][j] = 0.0f;

#pragma unroll 2
  for (int dc = 0; dc < 16; ++dc) {
    const int ko = dc * 32 + lh * 16;
    bf16x8 a[2], bb[2];
#pragma unroll
    for (int i = 0; i < 2; ++i) {
      a[i]  = *(const bf16x8*)((const char*)vt + ((size_t)(b * 256 + d2w + i * 32 + l31) * 4096 + tb) * 2 + ko);
      bb[i] = *(const bf16x8*)((const char*)kt + ((size_t)(b * 256 + d1w + i * 32 + l31) * 4096 + tb) * 2 + ko);
    }
#pragma unroll
    for (int i = 0; i < 2; ++i)
#pragma unroll
      for (int j = 0; j < 2; ++j)
        acc[i][j] = __builtin_amdgcn_mfma_f32_32x32x16_bf16(a[i], bb[j], acc[i][j], 0, 0, 0);
  }
  unsigned short* dst = mt + ((size_t)(b * 16 + jc) << 16);
#pragma unroll
  for (int i = 0; i < 2; ++i)
#pragma unroll
    for (int j = 0; j < 2; ++j)
#pragma unroll
      for (int reg = 0; reg < 16; ++reg) {
        int row = d2w + i * 32 + (reg & 3) + 8 * (reg >> 2) + 4 * lh;
        int col = d1w + j * 32 + l31;
        dst[row * 256 + col] = f2bf(acc[i][j][reg]);
      }
}

// ---------------------------------------------------------------------------
// scan: S_j = GC*(S_{j-1} + M_{j-1}), written in place to slot j-1 (bf16).
// Each thread owns 4 consecutive elements across all j -> race-free.
// ---------------------------------------------------------------------------
__global__ __launch_bounds__(256) void scan_kernel(unsigned short* __restrict__ mt) {
  const int e0 = (blockIdx.x * 256 + threadIdx.x) * 4;
  const int b = blockIdx.y;
  unsigned short* base = mt + ((size_t)b << 20);
  float s0 = 0.f, s1 = 0.f, s2 = 0.f, s3 = 0.f;
  for (int j = 1; j < 16; ++j) {
    unsigned short* p = base + ((size_t)(j - 1) << 16) + e0;
    uint2 mv = *(const uint2*)p;
    s0 = GC * (s0 + bf2f(mv.x & 0xffffu));
    s1 = GC * (s1 + bf2f(mv.x >> 16));
    s2 = GC * (s2 + bf2f(mv.y & 0xffffu));
    s3 = GC * (s3 + bf2f(mv.y >> 16));
    uint2 w;
    w.x = f2bf(s0) | ((unsigned int)f2bf(s1) << 16);
    w.y = f2bf(s2) | ((unsigned int)f2bf(s3) << 16);
    *(uint2*)p = w;
  }
}

// ---------------------------------------------------------------------------
// retc: out[b][s][:] = Q~ @ S_j (cross) + causal-intra(Q~ K~^T) @ V
// Block (st 64-s-tile, b); 4 waves = 2 s-groups x 2 t-phases. No LDS staging;
// K/V/S fragments direct from L2. Q hoisted. LDS only for final combine.
// ---------------------------------------------------------------------------
__global__ __launch_bounds__(256, 2) void retc_kernel(const unsigned short* __restrict__ qkv,
                                                      const unsigned short* __restrict__ vt,
                                                      const unsigned short* __restrict__ mt,
                                                      float* __restrict__ out) {
  __shared__ float cmb[2][32][256];
  const int tid = threadIdx.x;
  const int lane = tid & 63;
  const int wid = tid >> 6;
  const int tw = wid & 1, sw = wid >> 1;
  const int l31 = lane & 31, lh = lane >> 5;
  const int st = blockIdx.x;
  const int b = blockIdx.y;
  const int j = st >> 2;
  const int s0w = st * 64 + sw * 32;

  // hoist Q~ fragments (rows s0w+l31, full D)
  bf16x8 qf[16];
  {
    const char* qrow = (const char*)qkv + ((size_t)b * Sn + s0w + l31) * 1536;
#pragma unroll
    for (int dc = 0; dc < 16; ++dc)
      qf[dc] = *(const bf16x8*)(qrow + dc * 32 + lh * 16);
  }

  f32x16 acc[8];
#pragma unroll
  for (int i = 0; i < 8; ++i) acc[i] = 0.0f;

  // cross: acc += Q~ @ S_j   (ng halves split across tw)
  if (j > 0) {
    const char* Sj = (const char*)mt + ((size_t)(b * 16 + j - 1) << 17);
#pragma unroll 2
    for (int dc = 0; dc < 16; ++dc) {
#pragma unroll
      for (int g = 0; g < 4; ++g) {
        const int ng = tw * 4 + g;
        const int d2 = ng * 32 + l31;
        bf16x8 sbf = *(const bf16x8*)(Sj + d2 * 512 + dc * 32 + lh * 16);
        acc[ng] = __builtin_amdgcn_mfma_f32_32x32x16_bf16(qf[dc], sbf, acc[ng], 0, 0, 0);
      }
    }
  }

  // intra-chunk causal
  const int sg = s0w + l31;
  const int ksw = (l31 & 7) << 4;
  for (int tt = (st & ~3); tt <= st; ++tt) {
    const bool diag = (tt == st);
    if (diag && tw > sw) break;  // fully masked tile
    const int t0 = tt * 64 + tw * 32;
    const bool msk = diag && (tw == sw);

    f32x16 sacc = 0.0f;
    const char* krow = (const char*)qkv + ((size_t)b * Sn + t0 + l31) * 1536 + 512;
#pragma unroll 4
    for (int dc = 0; dc < 16; ++dc) {
      bf16x8 kf = *(const bf16x8*)(krow + ((dc * 32 + lh * 16) ^ ksw));
      sacc = __builtin_amdgcn_mfma_f32_32x32x16_bf16(kf, qf[dc], sacc, 0, 0, 0);
    }
    unsigned int P[8];
#pragma unroll
    for (int k = 0; k < 8; ++k) {
      const int r0 = 2 * k;
      float f0 = sacc[r0], f1 = sacc[r0 + 1];
      if (msk) {
        const int tg0 = t0 + (r0 & 3) + 8 * (r0 >> 2) + 4 * lh;
        f0 = (sg - tg0 >= 0) ? f0 : 0.0f;
        f1 = (sg - tg0 - 1 >= 0) ? f1 : 0.0f;
      }
      unsigned int pk;
      asm("v_cvt_pk_bf16_f32 %0, %1, %2" : "=v"(pk) : "v"(f0), "v"(f1));
      P[k] = pk;
    }
    asm volatile("v_permlane32_swap_b32 %0, %1" : "+v"(P[0]), "+v"(P[2]));
    asm volatile("v_permlane32_swap_b32 %0, %1" : "+v"(P[1]), "+v"(P[3]));
    asm volatile("v_permlane32_swap_b32 %0, %1" : "+v"(P[4]), "+v"(P[6]));
    asm volatile("v_permlane32_swap_b32 %0, %1" : "+v"(P[5]), "+v"(P[7]));
#pragma unroll
    for (int kc = 0; kc < 2; ++kc) {
      uint4 pw;
      pw.x = P[kc * 4 + 0]; pw.y = P[kc * 4 + 1];
      pw.z = P[kc * 4 + 2]; pw.w = P[kc * 4 + 3];
      bf16x8 pf = *(const bf16x8*)&pw;
#pragma unroll
      for (int ng = 0; ng < 8; ++ng) {
        const int d = ng * 32 + l31;
        bf16x8 vf = *(const bf16x8*)((const char*)vt +
            ((size_t)(b * 256 + d) * 4096 + t0) * 2 + kc * 32 + lh * 16);
        acc[ng] = __builtin_amdgcn_mfma_f32_32x32x16_bf16(pf, vf, acc[ng], 0, 0, 0);
      }
    }
  }

  // combine t-phases and store
  if (tw == 1) {
#pragma unroll
    for (int ng = 0; ng < 8; ++ng)
#pragma unroll
      for (int reg = 0; reg < 16; ++reg) {
        int sl = (reg & 3) + 8 * (reg >> 2) + 4 * lh;
        cmb[sw][sl][ng * 32 + l31] = acc[ng][reg];
      }
  }
  __syncthreads();
  if (tw == 0) {
#pragma unroll
    for (int ng = 0; ng < 8; ++ng)
#pragma unroll
      for (int reg = 0; reg < 16; ++reg) {
        int sl = (reg & 3) + 8 * (reg >> 2) + 4 * lh;
        int d = ng * 32 + l31;
        out[((size_t)(b * Sn + st * 64 + sw * 32 + sl)) * 256 + d] = acc[ng][reg] + cmb[sw][sl][d];
      }
  }
}

// ---------------------------------------------------------------------------
extern "C" void kernel_launch(void* const* d_in, const int* in_sizes, int n_in,
                              void* d_out, int out_size, void* d_ws, size_t ws_size,
                              hipStream_t stream) {
  (void)in_sizes; (void)n_in; (void)out_size; (void)ws_size;
  const float* x  = (const float*)d_in[0];
  const float* wq = (const float*)d_in[1];
  const float* wk = (const float*)d_in[2];
  const float* wv = (const float*)d_in[3];
  float* out = (float*)d_out;
  char* ws = (char*)d_ws;
  unsigned short* qkv = (unsigned short*)(ws);              // 25,165,824 B
  unsigned short* vt  = (unsigned short*)(ws + 25165824);   //  8,388,608 B
  unsigned short* kt  = (unsigned short*)(ws + 33554432);   //  8,388,608 B
  unsigned short* mt  = (unsigned short*)(ws + 41943040);   //  8,388,608 B (also S after scan)
  unsigned short* wt  = (unsigned short*)(ws + 41943040);   // alias: dead before mt written

  wt_build<<<dim3(32, 12), 256, 0, stream>>>(wq, wk, wv, wt);
  proj_kernel<<<dim3(128, 6), 256, 0, stream>>>(x, wt, qkv);
  xpos_kernel<<<2048, 256, 0, stream>>>(qkv);
  kvt_build<<<dim3(64, 4, 4), 256, 0, stream>>>(qkv, kt, vt);
  mbuild_kernel<<<dim3(16, 4, 4), 256, 0, stream>>>(kt, vt, mt);
  scan_kernel<<<dim3(64, 4), 256, 0, stream>>>(mt);
  retc_kernel<<<dim3(64, 4), 256, 0, stream>>>(qkv, vt, mt, out);
}

// Round 4
// 192.729 us; speedup vs baseline: 11.9034x; 1.1521x over previous
//
#include <hip/hip_runtime.h>
#include <cstddef>
#include <cstdint>

#define Bn 4
#define Sn 4096
#define Hn 2048
#define Dn 256

typedef float f32x16 __attribute__((ext_vector_type(16)));
typedef short bf16x8 __attribute__((ext_vector_type(8)));

#define AS3 __attribute__((address_space(3)))
#define AS1 __attribute__((address_space(1)))

// log2(0.96875); gamma^256
#define L2G -0.045803689613125f
#define GC 2.9526131e-4f

__device__ __forceinline__ unsigned short f2bf(float f) {
  union { float f; unsigned int u; } a; a.f = f;
  unsigned int r = a.u + 0x7fffu + ((a.u >> 16) & 1u);
  return (unsigned short)(r >> 16);
}
__device__ __forceinline__ float bf2f(unsigned int b) {
  union { unsigned int u; float f; } a; a.u = b << 16;
  return a.f;
}

// ---------------------------------------------------------------------------
// xbf: x[16384][2048] f32 -> bf16, plain row-major. Memory-bound.
// ---------------------------------------------------------------------------
__global__ __launch_bounds__(256) void xbf_kernel(const float* __restrict__ x,
                                                  unsigned short* __restrict__ xb) {
  const size_t g = (size_t)blockIdx.x * 256 + threadIdx.x;  // 2,097,152 threads
  const float* src = x + g * 16;
  unsigned short* dst = xb + g * 16;
  uint4 o0, o1;
  {
    float4 v0 = ((const float4*)src)[0];
    float4 v1 = ((const float4*)src)[1];
    float4 v2 = ((const float4*)src)[2];
    float4 v3 = ((const float4*)src)[3];
    o0.x = f2bf(v0.x) | ((unsigned int)f2bf(v0.y) << 16);
    o0.y = f2bf(v0.z) | ((unsigned int)f2bf(v0.w) << 16);
    o0.z = f2bf(v1.x) | ((unsigned int)f2bf(v1.y) << 16);
    o0.w = f2bf(v1.z) | ((unsigned int)f2bf(v1.w) << 16);
    o1.x = f2bf(v2.x) | ((unsigned int)f2bf(v2.y) << 16);
    o1.y = f2bf(v2.z) | ((unsigned int)f2bf(v2.w) << 16);
    o1.z = f2bf(v3.x) | ((unsigned int)f2bf(v3.y) << 16);
    o1.w = f2bf(v3.z) | ((unsigned int)f2bf(v3.w) << 16);
  }
  ((uint4*)dst)[0] = o0;
  ((uint4*)dst)[1] = o1;
}

// ---------------------------------------------------------------------------
// wt[768][2048] bf16 = [wq|wk|wv]^T, k-chunk (8 elems) swizzled: c' = c ^ (n&7)
// ---------------------------------------------------------------------------
__global__ __launch_bounds__(256) void wt_build(const float* __restrict__ wq,
                                                const float* __restrict__ wk,
                                                const float* __restrict__ wv,
                                                unsigned short* __restrict__ wt) {
  __shared__ __align__(16) unsigned short T[64][72];
  const int tid = threadIdx.x;
  const int k0 = blockIdx.x * 64;
  const int n0 = blockIdx.y * 64;
  const float* w = (n0 < 256) ? wq : (n0 < 512 ? wk : wv);
  const int nc0 = n0 & 255;
#pragma unroll
  for (int it = 0; it < 2; ++it) {
    int flat = it * 256 + tid;
    int r = flat >> 3, c8 = flat & 7;
    const float* src = w + (size_t)(k0 + r) * 256 + nc0 + c8 * 8;
    float4 v0 = *(const float4*)src;
    float4 v1 = *(const float4*)(src + 4);
    T[c8 * 8 + 0][r] = f2bf(v0.x); T[c8 * 8 + 1][r] = f2bf(v0.y);
    T[c8 * 8 + 2][r] = f2bf(v0.z); T[c8 * 8 + 3][r] = f2bf(v0.w);
    T[c8 * 8 + 4][r] = f2bf(v1.x); T[c8 * 8 + 5][r] = f2bf(v1.y);
    T[c8 * 8 + 6][r] = f2bf(v1.z); T[c8 * 8 + 7][r] = f2bf(v1.w);
  }
  __syncthreads();
#pragma unroll
  for (int it = 0; it < 2; ++it) {
    int flat = it * 256 + tid;
    int nr = flat >> 3, kc8 = flat & 7;
    int n = n0 + nr;
    int kc_sw = kc8 ^ (n & 7);
    uint4 val = *(const uint4*)&T[nr][kc8 * 8];
    *(uint4*)((char*)wt + (size_t)n * 4096 + (size_t)k0 * 2 + kc_sw * 16) = val;
  }
}

// ---------------------------------------------------------------------------
// proj2: qkv[16384][768] bf16 = xb @ wt^T. 128x128, BK=64, 4 waves, 32x32x16.
// Both A and B staged via global_load_lds(16B). A: linear LDS dest + XOR'd
// per-lane global source (involution), same XOR on frag read. B: pre-swizzled.
// K-half of qkv stored chunk-swizzled: c8' = c8 ^ (m&7).
// ---------------------------------------------------------------------------
__global__ __launch_bounds__(256, 3) void proj2_kernel(const unsigned short* __restrict__ xb,
                                                       const unsigned short* __restrict__ wt,
                                                       unsigned short* __restrict__ qkv) {
  __shared__ __align__(16) unsigned short As[128 * 64];
  __shared__ __align__(16) unsigned short Bs[128 * 64];
  const int tid = threadIdx.x;
  const int lane = tid & 63;
  const int wid = tid >> 6;
  const int wr = wid >> 1, wc = wid & 1;
  const int m0 = blockIdx.x * 128;
  const int n0 = blockIdx.y * 128;
  const int l31 = lane & 31, lh = lane >> 5;

  f32x16 acc[2][2];
#pragma unroll
  for (int i = 0; i < 2; ++i)
#pragma unroll
    for (int j = 0; j < 2; ++j) acc[i][j] = 0.0f;

  for (int k0 = 0; k0 < Hn; k0 += 64) {
    AS3 char* ldsa = (AS3 char*)As;
    AS3 char* ldsb = (AS3 char*)Bs;
#pragma unroll
    for (int i = 0; i < 4; ++i) {
      int ou = i * 4096 + wid * 1024;
      int o = ou + lane * 16;
      int row = o >> 7, colB = o & 127;
      const char* srcA = (const char*)xb + (size_t)(m0 + row) * 4096 + k0 * 2 + (colB ^ ((row & 7) << 4));
      __builtin_amdgcn_global_load_lds((const AS1 unsigned int*)srcA,
                                       (AS3 unsigned int*)(ldsa + ou), 16, 0, 0);
      const char* srcB = (const char*)wt + (size_t)(n0 + row) * 4096 + k0 * 2 + colB;
      __builtin_amdgcn_global_load_lds((const AS1 unsigned int*)srcB,
                                       (AS3 unsigned int*)(ldsb + ou), 16, 0, 0);
    }
    __syncthreads();
#pragma unroll
    for (int kc = 0; kc < 4; ++kc) {
      const int kb = kc * 32 + lh * 16;
      bf16x8 a[2], b[2];
#pragma unroll
      for (int i = 0; i < 2; ++i) {
        int mr = wr * 64 + i * 32 + l31;
        a[i] = *(const bf16x8*)((const char*)As + mr * 128 + (kb ^ ((mr & 7) << 4)));
        int nr = wc * 64 + i * 32 + l31;
        b[i] = *(const bf16x8*)((const char*)Bs + nr * 128 + (kb ^ ((nr & 7) << 4)));
      }
#pragma unroll
      for (int i = 0; i < 2; ++i)
#pragma unroll
        for (int j = 0; j < 2; ++j)
          acc[i][j] = __builtin_amdgcn_mfma_f32_32x32x16_bf16(a[i], b[j], acc[i][j], 0, 0, 0);
    }
    __syncthreads();
  }
  const bool khalf = (n0 >= 256 && n0 < 512);
#pragma unroll
  for (int i = 0; i < 2; ++i)
#pragma unroll
    for (int j = 0; j < 2; ++j)
#pragma unroll
      for (int reg = 0; reg < 16; ++reg) {
        int m = m0 + wr * 64 + i * 32 + (reg & 3) + 8 * (reg >> 2) + 4 * lh;
        int n = n0 + wc * 64 + j * 32 + l31;
        if (khalf) n = 256 + ((n - 256) ^ ((m & 7) << 3));
        qkv[(size_t)m * 768 + n] = f2bf(acc[i][j][reg]);
      }
}

// ---------------------------------------------------------------------------
// proj (fallback, f32 A in-loop convert): identical to round-3 version.
// ---------------------------------------------------------------------------
__global__ __launch_bounds__(256, 2) void proj_kernel(const float* __restrict__ x,
                                                      const unsigned short* __restrict__ wt,
                                                      unsigned short* __restrict__ qkv) {
  __shared__ __align__(16) unsigned short As[128 * 64];
  __shared__ __align__(16) unsigned short Bs[128 * 64];
  const int tid = threadIdx.x;
  const int lane = tid & 63;
  const int wid = tid >> 6;
  const int wr = wid >> 1, wc = wid & 1;
  const int m0 = blockIdx.x * 128;
  const int n0 = blockIdx.y * 128;
  const int l31 = lane & 31, lh = lane >> 5;

  f32x16 acc[2][2];
#pragma unroll
  for (int i = 0; i < 2; ++i)
#pragma unroll
    for (int j = 0; j < 2; ++j) acc[i][j] = 0.0f;

  for (int k0 = 0; k0 < Hn; k0 += 64) {
    {
      AS3 char* ldsb = (AS3 char*)Bs;
#pragma unroll
      for (int i = 0; i < 4; ++i) {
        int ou = i * 4096 + wid * 1024;
        int o = ou + lane * 16;
        int row = o >> 7, col = o & 127;
        const char* src = (const char*)wt + (size_t)(n0 + row) * 4096 + k0 * 2 + col;
        __builtin_amdgcn_global_load_lds((const AS1 unsigned int*)src,
                                         (AS3 unsigned int*)(ldsb + ou), 16, 0, 0);
      }
    }
#pragma unroll
    for (int i = 0; i < 4; ++i) {
      int o = i * 256 + tid;
      int row = o >> 3, c8 = o & 7;
      const float* src = x + (size_t)(m0 + row) * 2048 + k0 + c8 * 8;
      float4 v0 = *(const float4*)src;
      float4 v1 = *(const float4*)(src + 4);
      uint4 val;
      val.x = f2bf(v0.x) | ((unsigned int)f2bf(v0.y) << 16);
      val.y = f2bf(v0.z) | ((unsigned int)f2bf(v0.w) << 16);
      val.z = f2bf(v1.x) | ((unsigned int)f2bf(v1.y) << 16);
      val.w = f2bf(v1.z) | ((unsigned int)f2bf(v1.w) << 16);
      *(uint4*)((char*)As + row * 128 + ((c8 * 16) ^ ((row & 7) << 4))) = val;
    }
    __syncthreads();
#pragma unroll
    for (int kc = 0; kc < 4; ++kc) {
      const int kb = kc * 32 + lh * 16;
      bf16x8 a[2], b[2];
#pragma unroll
      for (int i = 0; i < 2; ++i) {
        int mr = wr * 64 + i * 32 + l31;
        a[i] = *(const bf16x8*)((const char*)As + mr * 128 + (kb ^ ((mr & 7) << 4)));
        int nr = wc * 64 + i * 32 + l31;
        b[i] = *(const bf16x8*)((const char*)Bs + nr * 128 + (kb ^ ((nr & 7) << 4)));
      }
#pragma unroll
      for (int i = 0; i < 2; ++i)
#pragma unroll
        for (int j = 0; j < 2; ++j)
          acc[i][j] = __builtin_amdgcn_mfma_f32_32x32x16_bf16(a[i], b[j], acc[i][j], 0, 0, 0);
    }
    __syncthreads();
  }
  const bool khalf = (n0 >= 256 && n0 < 512);
#pragma unroll
  for (int i = 0; i < 2; ++i)
#pragma unroll
    for (int j = 0; j < 2; ++j)
#pragma unroll
      for (int reg = 0; reg < 16; ++reg) {
        int m = m0 + wr * 64 + i * 32 + (reg & 3) + 8 * (reg >> 2) + 4 * lh;
        int n = n0 + wc * 64 + j * 32 + l31;
        if (khalf) n = 256 + ((n - 256) ^ ((m & 7) << 3));
        qkv[(size_t)m * 768 + n] = f2bf(acc[i][j][reg]);
      }
}

// ---------------------------------------------------------------------------
// xpos rotary + chunk decay folding, in place on bf16 qkv.
// ---------------------------------------------------------------------------
__global__ __launch_bounds__(256) void xpos_kernel(unsigned short* __restrict__ qkv) {
  const int g = blockIdx.x * 256 + threadIdx.x;
  const int m = g >> 5;
  const int c = g & 31;
  const float s = (float)(m & (Sn - 1));
  unsigned short* qrow = qkv + (size_t)m * 768;
  const int csw = c ^ (m & 7);
  uint4 qv = *(uint4*)(qrow + c * 8);
  uint4 kv = *(uint4*)(qrow + 256 + csw * 8);
  unsigned int* qu = (unsigned int*)&qv;
  unsigned int* ku = (unsigned int*)&kv;
  const float pw = (s - 2048.0f) * (1.0f / 512.0f);
  const float gp = exp2f((float)(m & 255) * L2G);  // gamma^tau
#pragma unroll
  for (int p = 0; p < 4; ++p) {
    const int jp = c * 4 + p;
    const float invf = exp2f((float)jp * (-13.287712379549449f / 128.0f));
    float sn, cs;
    sincosf(s * invf, &sn, &cs);
    const float sv = (2.0f * jp + 102.4f) * (1.0f / 358.4f);
    const float scq = exp2f(pw * log2f(sv)) * gp;
    const float sci = 1.0f / scq;
    float q0 = bf2f(qu[p] & 0xffffu), q1 = bf2f(qu[p] >> 16);
    float k0 = bf2f(ku[p] & 0xffffu), k1 = bf2f(ku[p] >> 16);
    float q0r = (q0 * cs - q1 * sn) * scq;
    float q1r = (q1 * cs + q0 * sn) * scq;
    float k0r = (k0 * cs - k1 * sn) * sci;
    float k1r = (k1 * cs + k0 * sn) * sci;
    qu[p] = f2bf(q0r) | ((unsigned int)f2bf(q1r) << 16);
    ku[p] = f2bf(k0r) | ((unsigned int)f2bf(k1r) << 16);
  }
  *(uint4*)(qrow + c * 8) = qv;
  *(uint4*)(qrow + 256 + csw * 8) = kv;
}

// ---------------------------------------------------------------------------
// kt[b][d][t] = k~[b][t][d] (deswizzled), vt[b][d][t] = v[b][t][d]
// ---------------------------------------------------------------------------
__global__ __launch_bounds__(256) void kvt_build(const unsigned short* __restrict__ qkv,
                                                 unsigned short* __restrict__ kt,
                                                 unsigned short* __restrict__ vt) {
  __shared__ __align__(16) unsigned short Tk[64][72];
  __shared__ __align__(16) unsigned short Tv[64][72];
  const int tid = threadIdx.x;
  const int t0 = blockIdx.x * 64;
  const int d0 = blockIdx.y * 64;
  const int b = blockIdx.z;
  const size_t rowb = ((size_t)b * Sn + t0) * 1536;
#pragma unroll
  for (int it = 0; it < 2; ++it) {
    int flat = it * 256 + tid;
    int r = flat >> 3, c8 = flat & 7;
    int kc = (d0 >> 3) + c8;
    int kcs = kc ^ (r & 7);
    uint4 kvv = *(const uint4*)((const char*)qkv + rowb + (size_t)r * 1536 + 512 + kcs * 16);
    uint4 vvv = *(const uint4*)((const char*)qkv + rowb + (size_t)r * 1536 + 1024 + (size_t)(d0 + c8 * 8) * 2);
    const unsigned short* ke = (const unsigned short*)&kvv;
    const unsigned short* ve = (const unsigned short*)&vvv;
#pragma unroll
    for (int e = 0; e < 8; ++e) { Tk[c8 * 8 + e][r] = ke[e]; Tv[c8 * 8 + e][r] = ve[e]; }
  }
  __syncthreads();
#pragma unroll
  for (int it = 0; it < 2; ++it) {
    int flat = it * 256 + tid;
    int dr = flat >> 3, tc8 = flat & 7;
    *(uint4*)(kt + (size_t)(b * 256 + d0 + dr) * 4096 + t0 + tc8 * 8) = *(const uint4*)&Tk[dr][tc8 * 8];
    *(uint4*)(vt + (size_t)(b * 256 + d0 + dr) * 4096 + t0 + tc8 * 8) = *(const uint4*)&Tv[dr][tc8 * 8];
  }
}

// ---------------------------------------------------------------------------
// mbuild: Mt[b][j][d2][d1] = sum_t V[t][d2] * K~[t][d1]  (= M^T), bf16 out.
// ---------------------------------------------------------------------------
__global__ __launch_bounds__(256) void mbuild_kernel(const unsigned short* __restrict__ kt,
                                                     const unsigned short* __restrict__ vt,
                                                     unsigned short* __restrict__ mt) {
  const int tid = threadIdx.x;
  const int lane = tid & 63;
  const int wid = tid >> 6;
  const int l31 = lane & 31, lh = lane >> 5;
  const int jc = blockIdx.x;
  const int quad = blockIdx.y;
  const int b = blockIdx.z;
  const int d2w = ((quad >> 1) * 2 + (wid >> 1)) * 64;
  const int d1w = ((quad & 1) * 2 + (wid & 1)) * 64;
  const size_t tb = (size_t)jc * 256;

  f32x16 acc[2][2];
#pragma unroll
  for (int i = 0; i < 2; ++i)
#pragma unroll
    for (int j = 0; j < 2; ++j) acc[i][j] = 0.0f;

#pragma unroll 2
  for (int dc = 0; dc < 16; ++dc) {
    const int ko = dc * 32 + lh * 16;
    bf16x8 a[2], bb[2];
#pragma unroll
    for (int i = 0; i < 2; ++i) {
      a[i]  = *(const bf16x8*)((const char*)vt + ((size_t)(b * 256 + d2w + i * 32 + l31) * 4096 + tb) * 2 + ko);
      bb[i] = *(const bf16x8*)((const char*)kt + ((size_t)(b * 256 + d1w + i * 32 + l31) * 4096 + tb) * 2 + ko);
    }
#pragma unroll
    for (int i = 0; i < 2; ++i)
#pragma unroll
      for (int j = 0; j < 2; ++j)
        acc[i][j] = __builtin_amdgcn_mfma_f32_32x32x16_bf16(a[i], bb[j], acc[i][j], 0, 0, 0);
  }
  unsigned short* dst = mt + ((size_t)(b * 16 + jc) << 16);
#pragma unroll
  for (int i = 0; i < 2; ++i)
#pragma unroll
    for (int j = 0; j < 2; ++j)
#pragma unroll
      for (int reg = 0; reg < 16; ++reg) {
        int row = d2w + i * 32 + (reg & 3) + 8 * (reg >> 2) + 4 * lh;
        int col = d1w + j * 32 + l31;
        dst[row * 256 + col] = f2bf(acc[i][j][reg]);
      }
}

// ---------------------------------------------------------------------------
// scan: S_j = GC*(S_{j-1} + M_{j-1}), in place to slot j-1 (bf16).
// ---------------------------------------------------------------------------
__global__ __launch_bounds__(256) void scan_kernel(unsigned short* __restrict__ mt) {
  const int e0 = (blockIdx.x * 256 + threadIdx.x) * 4;
  const int b = blockIdx.y;
  unsigned short* base = mt + ((size_t)b << 20);
  float s0 = 0.f, s1 = 0.f, s2 = 0.f, s3 = 0.f;
  for (int j = 1; j < 16; ++j) {
    unsigned short* p = base + ((size_t)(j - 1) << 16) + e0;
    uint2 mv = *(const uint2*)p;
    s0 = GC * (s0 + bf2f(mv.x & 0xffffu));
    s1 = GC * (s1 + bf2f(mv.x >> 16));
    s2 = GC * (s2 + bf2f(mv.y & 0xffffu));
    s3 = GC * (s3 + bf2f(mv.y >> 16));
    uint2 w;
    w.x = f2bf(s0) | ((unsigned int)f2bf(s1) << 16);
    w.y = f2bf(s2) | ((unsigned int)f2bf(s3) << 16);
    *(uint2*)p = w;
  }
}

// ---------------------------------------------------------------------------
// retc: out = Q~ @ S_j (cross) + causal-intra(Q~ K~^T) @ V
// ---------------------------------------------------------------------------
__global__ __launch_bounds__(256, 2) void retc_kernel(const unsigned short* __restrict__ qkv,
                                                      const unsigned short* __restrict__ vt,
                                                      const unsigned short* __restrict__ mt,
                                                      float* __restrict__ out) {
  __shared__ float cmb[2][32][256];
  const int tid = threadIdx.x;
  const int lane = tid & 63;
  const int wid = tid >> 6;
  const int tw = wid & 1, sw = wid >> 1;
  const int l31 = lane & 31, lh = lane >> 5;
  const int st = blockIdx.x;
  const int b = blockIdx.y;
  const int j = st >> 2;
  const int s0w = st * 64 + sw * 32;

  bf16x8 qf[16];
  {
    const char* qrow = (const char*)qkv + ((size_t)b * Sn + s0w + l31) * 1536;
#pragma unroll
    for (int dc = 0; dc < 16; ++dc)
      qf[dc] = *(const bf16x8*)(qrow + dc * 32 + lh * 16);
  }

  f32x16 acc[8];
#pragma unroll
  for (int i = 0; i < 8; ++i) acc[i] = 0.0f;

  if (j > 0) {
    const char* Sj = (const char*)mt + ((size_t)(b * 16 + j - 1) << 17);
#pragma unroll 2
    for (int dc = 0; dc < 16; ++dc) {
#pragma unroll
      for (int g = 0; g < 4; ++g) {
        const int ng = tw * 4 + g;
        const int d2 = ng * 32 + l31;
        bf16x8 sbf = *(const bf16x8*)(Sj + d2 * 512 + dc * 32 + lh * 16);
        acc[ng] = __builtin_amdgcn_mfma_f32_32x32x16_bf16(qf[dc], sbf, acc[ng], 0, 0, 0);
      }
    }
  }

  const int sg = s0w + l31;
  const int ksw = (l31 & 7) << 4;
  for (int tt = (st & ~3); tt <= st; ++tt) {
    const bool diag = (tt == st);
    if (diag && tw > sw) break;
    const int t0 = tt * 64 + tw * 32;
    const bool msk = diag && (tw == sw);

    f32x16 sacc = 0.0f;
    const char* krow = (const char*)qkv + ((size_t)b * Sn + t0 + l31) * 1536 + 512;
#pragma unroll 4
    for (int dc = 0; dc < 16; ++dc) {
      bf16x8 kf = *(const bf16x8*)(krow + ((dc * 32 + lh * 16) ^ ksw));
      sacc = __builtin_amdgcn_mfma_f32_32x32x16_bf16(kf, qf[dc], sacc, 0, 0, 0);
    }
    unsigned int P[8];
#pragma unroll
    for (int k = 0; k < 8; ++k) {
      const int r0 = 2 * k;
      float f0 = sacc[r0], f1 = sacc[r0 + 1];
      if (msk) {
        const int tg0 = t0 + (r0 & 3) + 8 * (r0 >> 2) + 4 * lh;
        f0 = (sg - tg0 >= 0) ? f0 : 0.0f;
        f1 = (sg - tg0 - 1 >= 0) ? f1 : 0.0f;
      }
      unsigned int pk;
      asm("v_cvt_pk_bf16_f32 %0, %1, %2" : "=v"(pk) : "v"(f0), "v"(f1));
      P[k] = pk;
    }
    asm volatile("v_permlane32_swap_b32 %0, %1" : "+v"(P[0]), "+v"(P[2]));
    asm volatile("v_permlane32_swap_b32 %0, %1" : "+v"(P[1]), "+v"(P[3]));
    asm volatile("v_permlane32_swap_b32 %0, %1" : "+v"(P[4]), "+v"(P[6]));
    asm volatile("v_permlane32_swap_b32 %0, %1" : "+v"(P[5]), "+v"(P[7]));
#pragma unroll
    for (int kc = 0; kc < 2; ++kc) {
      uint4 pw;
      pw.x = P[kc * 4 + 0]; pw.y = P[kc * 4 + 1];
      pw.z = P[kc * 4 + 2]; pw.w = P[kc * 4 + 3];
      bf16x8 pf = *(const bf16x8*)&pw;
#pragma unroll
      for (int ng = 0; ng < 8; ++ng) {
        const int d = ng * 32 + l31;
        bf16x8 vf = *(const bf16x8*)((const char*)vt +
            ((size_t)(b * 256 + d) * 4096 + t0) * 2 + kc * 32 + lh * 16);
        acc[ng] = __builtin_amdgcn_mfma_f32_32x32x16_bf16(pf, vf, acc[ng], 0, 0, 0);
      }
    }
  }

  if (tw == 1) {
#pragma unroll
    for (int ng = 0; ng < 8; ++ng)
#pragma unroll
      for (int reg = 0; reg < 16; ++reg) {
        int sl = (reg & 3) + 8 * (reg >> 2) + 4 * lh;
        cmb[sw][sl][ng * 32 + l31] = acc[ng][reg];
      }
  }
  __syncthreads();
  if (tw == 0) {
#pragma unroll
    for (int ng = 0; ng < 8; ++ng)
#pragma unroll
      for (int reg = 0; reg < 16; ++reg) {
        int sl = (reg & 3) + 8 * (reg >> 2) + 4 * lh;
        int d = ng * 32 + l31;
        out[((size_t)(b * Sn + st * 64 + sw * 32 + sl)) * 256 + d] = acc[ng][reg] + cmb[sw][sl][d];
      }
  }
}

// ---------------------------------------------------------------------------
extern "C" void kernel_launch(void* const* d_in, const int* in_sizes, int n_in,
                              void* d_out, int out_size, void* d_ws, size_t ws_size,
                              hipStream_t stream) {
  (void)in_sizes; (void)n_in; (void)out_size;
  const float* x  = (const float*)d_in[0];
  const float* wq = (const float*)d_in[1];
  const float* wk = (const float*)d_in[2];
  const float* wv = (const float*)d_in[3];
  float* out = (float*)d_out;
  char* ws = (char*)d_ws;

  // Common region (both paths): qkv@0; kt/vt/mt fixed offsets.
  unsigned short* qkv = (unsigned short*)(ws);              // 25,165,824 B
  unsigned short* vt  = (unsigned short*)(ws + 25165824);   //  8,388,608 B
  unsigned short* kt  = (unsigned short*)(ws + 33554432);   //  8,388,608 B
  unsigned short* mt  = (unsigned short*)(ws + 41943040);   //  8,388,608 B

  const size_t NEED_BIG = 95420416;  // qkv + xb(67.1MB, aliases kt/vt/mt) + wt
  if (ws_size >= NEED_BIG) {
    unsigned short* xb = (unsigned short*)(ws + 25165824);  // 67,108,864 B (dead after proj2)
    unsigned short* wt = (unsigned short*)(ws + 92274688);  //  3,145,728 B (live through proj2)
    xbf_kernel<<<8192, 256, 0, stream>>>(x, xb);
    wt_build<<<dim3(32, 12), 256, 0, stream>>>(wq, wk, wv, wt);
    proj2_kernel<<<dim3(128, 6), 256, 0, stream>>>(xb, wt, qkv);
  } else {
    unsigned short* wt = (unsigned short*)(ws + 41943040);  // alias mt: dead before mt written
    wt_build<<<dim3(32, 12), 256, 0, stream>>>(wq, wk, wv, wt);
    proj_kernel<<<dim3(128, 6), 256, 0, stream>>>(x, wt, qkv);
  }
  xpos_kernel<<<2048, 256, 0, stream>>>(qkv);
  kvt_build<<<dim3(64, 4, 4), 256, 0, stream>>>(qkv, kt, vt);
  mbuild_kernel<<<dim3(16, 4, 4), 256, 0, stream>>>(kt, vt, mt);
  scan_kernel<<<dim3(64, 4), 256, 0, stream>>>(mt);
  retc_kernel<<<dim3(64, 4), 256, 0, stream>>>(qkv, vt, mt, out);
}

// Round 5
// 185.985 us; speedup vs baseline: 12.3351x; 1.0363x over previous
//
#include <hip/hip_runtime.h>
#include <cstddef>
#include <cstdint>

#define Bn 4
#define Sn 4096
#define Hn 2048
#define Dn 256

typedef float f32x16 __attribute__((ext_vector_type(16)));
typedef short bf16x8 __attribute__((ext_vector_type(8)));

#define AS3 __attribute__((address_space(3)))
#define AS1 __attribute__((address_space(1)))

// log2(0.96875); gamma^256
#define L2G -0.045803689613125f
#define GC 2.9526131e-4f

__device__ __forceinline__ unsigned short f2bf(float f) {
  union { float f; unsigned int u; } a; a.f = f;
  unsigned int r = a.u + 0x7fffu + ((a.u >> 16) & 1u);
  return (unsigned short)(r >> 16);
}
__device__ __forceinline__ float bf2f(unsigned int b) {
  union { unsigned int u; float f; } a; a.u = b << 16;
  return a.f;
}

// ---------------------------------------------------------------------------
// xbf: x[16384][2048] f32 -> bf16, plain row-major. Memory-bound.
// ---------------------------------------------------------------------------
__global__ __launch_bounds__(256) void xbf_kernel(const float* __restrict__ x,
                                                  unsigned short* __restrict__ xb) {
  const size_t g = (size_t)blockIdx.x * 256 + threadIdx.x;
  const float* src = x + g * 16;
  unsigned short* dst = xb + g * 16;
  uint4 o0, o1;
  {
    float4 v0 = ((const float4*)src)[0];
    float4 v1 = ((const float4*)src)[1];
    float4 v2 = ((const float4*)src)[2];
    float4 v3 = ((const float4*)src)[3];
    o0.x = f2bf(v0.x) | ((unsigned int)f2bf(v0.y) << 16);
    o0.y = f2bf(v0.z) | ((unsigned int)f2bf(v0.w) << 16);
    o0.z = f2bf(v1.x) | ((unsigned int)f2bf(v1.y) << 16);
    o0.w = f2bf(v1.z) | ((unsigned int)f2bf(v1.w) << 16);
    o1.x = f2bf(v2.x) | ((unsigned int)f2bf(v2.y) << 16);
    o1.y = f2bf(v2.z) | ((unsigned int)f2bf(v2.w) << 16);
    o1.z = f2bf(v3.x) | ((unsigned int)f2bf(v3.y) << 16);
    o1.w = f2bf(v3.z) | ((unsigned int)f2bf(v3.w) << 16);
  }
  ((uint4*)dst)[0] = o0;
  ((uint4*)dst)[1] = o1;
}

// ---------------------------------------------------------------------------
// wt[768][2048] bf16 = [wq|wk|wv]^T, k-chunk (8 elems) swizzled: c' = c ^ (n&7)
// ---------------------------------------------------------------------------
__global__ __launch_bounds__(256) void wt_build(const float* __restrict__ wq,
                                                const float* __restrict__ wk,
                                                const float* __restrict__ wv,
                                                unsigned short* __restrict__ wt) {
  __shared__ __align__(16) unsigned short T[64][72];
  const int tid = threadIdx.x;
  const int k0 = blockIdx.x * 64;
  const int n0 = blockIdx.y * 64;
  const float* w = (n0 < 256) ? wq : (n0 < 512 ? wk : wv);
  const int nc0 = n0 & 255;
#pragma unroll
  for (int it = 0; it < 2; ++it) {
    int flat = it * 256 + tid;
    int r = flat >> 3, c8 = flat & 7;
    const float* src = w + (size_t)(k0 + r) * 256 + nc0 + c8 * 8;
    float4 v0 = *(const float4*)src;
    float4 v1 = *(const float4*)(src + 4);
    T[c8 * 8 + 0][r] = f2bf(v0.x); T[c8 * 8 + 1][r] = f2bf(v0.y);
    T[c8 * 8 + 2][r] = f2bf(v0.z); T[c8 * 8 + 3][r] = f2bf(v0.w);
    T[c8 * 8 + 4][r] = f2bf(v1.x); T[c8 * 8 + 5][r] = f2bf(v1.y);
    T[c8 * 8 + 6][r] = f2bf(v1.z); T[c8 * 8 + 7][r] = f2bf(v1.w);
  }
  __syncthreads();
#pragma unroll
  for (int it = 0; it < 2; ++it) {
    int flat = it * 256 + tid;
    int nr = flat >> 3, kc8 = flat & 7;
    int n = n0 + nr;
    int kc_sw = kc8 ^ (n & 7);
    uint4 val = *(const uint4*)&T[nr][kc8 * 8];
    *(uint4*)((char*)wt + (size_t)n * 4096 + (size_t)k0 * 2 + kc_sw * 16) = val;
  }
}

// ---------------------------------------------------------------------------
// proj2: qkv[16384][768] bf16 = xb @ wt^T. 128x128, BK=64, 4 waves, 32x32x16.
// ---------------------------------------------------------------------------
__global__ __launch_bounds__(256, 3) void proj2_kernel(const unsigned short* __restrict__ xb,
                                                       const unsigned short* __restrict__ wt,
                                                       unsigned short* __restrict__ qkv) {
  __shared__ __align__(16) unsigned short As[128 * 64];
  __shared__ __align__(16) unsigned short Bs[128 * 64];
  const int tid = threadIdx.x;
  const int lane = tid & 63;
  const int wid = tid >> 6;
  const int wr = wid >> 1, wc = wid & 1;
  const int m0 = blockIdx.x * 128;
  const int n0 = blockIdx.y * 128;
  const int l31 = lane & 31, lh = lane >> 5;

  f32x16 acc[2][2];
#pragma unroll
  for (int i = 0; i < 2; ++i)
#pragma unroll
    for (int j = 0; j < 2; ++j) acc[i][j] = 0.0f;

  for (int k0 = 0; k0 < Hn; k0 += 64) {
    AS3 char* ldsa = (AS3 char*)As;
    AS3 char* ldsb = (AS3 char*)Bs;
#pragma unroll
    for (int i = 0; i < 4; ++i) {
      int ou = i * 4096 + wid * 1024;
      int o = ou + lane * 16;
      int row = o >> 7, colB = o & 127;
      const char* srcA = (const char*)xb + (size_t)(m0 + row) * 4096 + k0 * 2 + (colB ^ ((row & 7) << 4));
      __builtin_amdgcn_global_load_lds((const AS1 unsigned int*)srcA,
                                       (AS3 unsigned int*)(ldsa + ou), 16, 0, 0);
      const char* srcB = (const char*)wt + (size_t)(n0 + row) * 4096 + k0 * 2 + colB;
      __builtin_amdgcn_global_load_lds((const AS1 unsigned int*)srcB,
                                       (AS3 unsigned int*)(ldsb + ou), 16, 0, 0);
    }
    __syncthreads();
#pragma unroll
    for (int kc = 0; kc < 4; ++kc) {
      const int kb = kc * 32 + lh * 16;
      bf16x8 a[2], b[2];
#pragma unroll
      for (int i = 0; i < 2; ++i) {
        int mr = wr * 64 + i * 32 + l31;
        a[i] = *(const bf16x8*)((const char*)As + mr * 128 + (kb ^ ((mr & 7) << 4)));
        int nr = wc * 64 + i * 32 + l31;
        b[i] = *(const bf16x8*)((const char*)Bs + nr * 128 + (kb ^ ((nr & 7) << 4)));
      }
#pragma unroll
      for (int i = 0; i < 2; ++i)
#pragma unroll
        for (int j = 0; j < 2; ++j)
          acc[i][j] = __builtin_amdgcn_mfma_f32_32x32x16_bf16(a[i], b[j], acc[i][j], 0, 0, 0);
    }
    __syncthreads();
  }
  const bool khalf = (n0 >= 256 && n0 < 512);
#pragma unroll
  for (int i = 0; i < 2; ++i)
#pragma unroll
    for (int j = 0; j < 2; ++j)
#pragma unroll
      for (int reg = 0; reg < 16; ++reg) {
        int m = m0 + wr * 64 + i * 32 + (reg & 3) + 8 * (reg >> 2) + 4 * lh;
        int n = n0 + wc * 64 + j * 32 + l31;
        if (khalf) n = 256 + ((n - 256) ^ ((m & 7) << 3));
        qkv[(size_t)m * 768 + n] = f2bf(acc[i][j][reg]);
      }
}

// ---------------------------------------------------------------------------
// proj (fallback for small ws): round-3 version, f32 A in-loop convert.
// ---------------------------------------------------------------------------
__global__ __launch_bounds__(256, 2) void proj_kernel(const float* __restrict__ x,
                                                      const unsigned short* __restrict__ wt,
                                                      unsigned short* __restrict__ qkv) {
  __shared__ __align__(16) unsigned short As[128 * 64];
  __shared__ __align__(16) unsigned short Bs[128 * 64];
  const int tid = threadIdx.x;
  const int lane = tid & 63;
  const int wid = tid >> 6;
  const int wr = wid >> 1, wc = wid & 1;
  const int m0 = blockIdx.x * 128;
  const int n0 = blockIdx.y * 128;
  const int l31 = lane & 31, lh = lane >> 5;

  f32x16 acc[2][2];
#pragma unroll
  for (int i = 0; i < 2; ++i)
#pragma unroll
    for (int j = 0; j < 2; ++j) acc[i][j] = 0.0f;

  for (int k0 = 0; k0 < Hn; k0 += 64) {
    {
      AS3 char* ldsb = (AS3 char*)Bs;
#pragma unroll
      for (int i = 0; i < 4; ++i) {
        int ou = i * 4096 + wid * 1024;
        int o = ou + lane * 16;
        int row = o >> 7, col = o & 127;
        const char* src = (const char*)wt + (size_t)(n0 + row) * 4096 + k0 * 2 + col;
        __builtin_amdgcn_global_load_lds((const AS1 unsigned int*)src,
                                         (AS3 unsigned int*)(ldsb + ou), 16, 0, 0);
      }
    }
#pragma unroll
    for (int i = 0; i < 4; ++i) {
      int o = i * 256 + tid;
      int row = o >> 3, c8 = o & 7;
      const float* src = x + (size_t)(m0 + row) * 2048 + k0 + c8 * 8;
      float4 v0 = *(const float4*)src;
      float4 v1 = *(const float4*)(src + 4);
      uint4 val;
      val.x = f2bf(v0.x) | ((unsigned int)f2bf(v0.y) << 16);
      val.y = f2bf(v0.z) | ((unsigned int)f2bf(v0.w) << 16);
      val.z = f2bf(v1.x) | ((unsigned int)f2bf(v1.y) << 16);
      val.w = f2bf(v1.z) | ((unsigned int)f2bf(v1.w) << 16);
      *(uint4*)((char*)As + row * 128 + ((c8 * 16) ^ ((row & 7) << 4))) = val;
    }
    __syncthreads();
#pragma unroll
    for (int kc = 0; kc < 4; ++kc) {
      const int kb = kc * 32 + lh * 16;
      bf16x8 a[2], b[2];
#pragma unroll
      for (int i = 0; i < 2; ++i) {
        int mr = wr * 64 + i * 32 + l31;
        a[i] = *(const bf16x8*)((const char*)As + mr * 128 + (kb ^ ((mr & 7) << 4)));
        int nr = wc * 64 + i * 32 + l31;
        b[i] = *(const bf16x8*)((const char*)Bs + nr * 128 + (kb ^ ((nr & 7) << 4)));
      }
#pragma unroll
      for (int i = 0; i < 2; ++i)
#pragma unroll
        for (int j = 0; j < 2; ++j)
          acc[i][j] = __builtin_amdgcn_mfma_f32_32x32x16_bf16(a[i], b[j], acc[i][j], 0, 0, 0);
    }
    __syncthreads();
  }
  const bool khalf = (n0 >= 256 && n0 < 512);
#pragma unroll
  for (int i = 0; i < 2; ++i)
#pragma unroll
    for (int j = 0; j < 2; ++j)
#pragma unroll
      for (int reg = 0; reg < 16; ++reg) {
        int m = m0 + wr * 64 + i * 32 + (reg & 3) + 8 * (reg >> 2) + 4 * lh;
        int n = n0 + wc * 64 + j * 32 + l31;
        if (khalf) n = 256 + ((n - 256) ^ ((m & 7) << 3));
        qkv[(size_t)m * 768 + n] = f2bf(acc[i][j][reg]);
      }
}

// ---------------------------------------------------------------------------
// xpos rotary + chunk decay folding, in place on bf16 qkv.
// ---------------------------------------------------------------------------
__global__ __launch_bounds__(256) void xpos_kernel(unsigned short* __restrict__ qkv) {
  const int g = blockIdx.x * 256 + threadIdx.x;
  const int m = g >> 5;
  const int c = g & 31;
  const float s = (float)(m & (Sn - 1));
  unsigned short* qrow = qkv + (size_t)m * 768;
  const int csw = c ^ (m & 7);
  uint4 qv = *(uint4*)(qrow + c * 8);
  uint4 kv = *(uint4*)(qrow + 256 + csw * 8);
  unsigned int* qu = (unsigned int*)&qv;
  unsigned int* ku = (unsigned int*)&kv;
  const float pw = (s - 2048.0f) * (1.0f / 512.0f);
  const float gp = exp2f((float)(m & 255) * L2G);  // gamma^tau
#pragma unroll
  for (int p = 0; p < 4; ++p) {
    const int jp = c * 4 + p;
    const float invf = exp2f((float)jp * (-13.287712379549449f / 128.0f));
    float sn, cs;
    sincosf(s * invf, &sn, &cs);
    const float sv = (2.0f * jp + 102.4f) * (1.0f / 358.4f);
    const float scq = exp2f(pw * log2f(sv)) * gp;
    const float sci = 1.0f / scq;
    float q0 = bf2f(qu[p] & 0xffffu), q1 = bf2f(qu[p] >> 16);
    float k0 = bf2f(ku[p] & 0xffffu), k1 = bf2f(ku[p] >> 16);
    float q0r = (q0 * cs - q1 * sn) * scq;
    float q1r = (q1 * cs + q0 * sn) * scq;
    float k0r = (k0 * cs - k1 * sn) * sci;
    float k1r = (k1 * cs + k0 * sn) * sci;
    qu[p] = f2bf(q0r) | ((unsigned int)f2bf(q1r) << 16);
    ku[p] = f2bf(k0r) | ((unsigned int)f2bf(k1r) << 16);
  }
  *(uint4*)(qrow + c * 8) = qv;
  *(uint4*)(qrow + 256 + csw * 8) = kv;
}

// ---------------------------------------------------------------------------
// kt[b][d][t] = k~[b][t][d] (deswizzled), vt[b][d][t] = v[b][t][d]
// ---------------------------------------------------------------------------
__global__ __launch_bounds__(256) void kvt_build(const unsigned short* __restrict__ qkv,
                                                 unsigned short* __restrict__ kt,
                                                 unsigned short* __restrict__ vt) {
  __shared__ __align__(16) unsigned short Tk[64][72];
  __shared__ __align__(16) unsigned short Tv[64][72];
  const int tid = threadIdx.x;
  const int t0 = blockIdx.x * 64;
  const int d0 = blockIdx.y * 64;
  const int b = blockIdx.z;
  const size_t rowb = ((size_t)b * Sn + t0) * 1536;
#pragma unroll
  for (int it = 0; it < 2; ++it) {
    int flat = it * 256 + tid;
    int r = flat >> 3, c8 = flat & 7;
    int kc = (d0 >> 3) + c8;
    int kcs = kc ^ (r & 7);
    uint4 kvv = *(const uint4*)((const char*)qkv + rowb + (size_t)r * 1536 + 512 + kcs * 16);
    uint4 vvv = *(const uint4*)((const char*)qkv + rowb + (size_t)r * 1536 + 1024 + (size_t)(d0 + c8 * 8) * 2);
    const unsigned short* ke = (const unsigned short*)&kvv;
    const unsigned short* ve = (const unsigned short*)&vvv;
#pragma unroll
    for (int e = 0; e < 8; ++e) { Tk[c8 * 8 + e][r] = ke[e]; Tv[c8 * 8 + e][r] = ve[e]; }
  }
  __syncthreads();
#pragma unroll
  for (int it = 0; it < 2; ++it) {
    int flat = it * 256 + tid;
    int dr = flat >> 3, tc8 = flat & 7;
    *(uint4*)(kt + (size_t)(b * 256 + d0 + dr) * 4096 + t0 + tc8 * 8) = *(const uint4*)&Tk[dr][tc8 * 8];
    *(uint4*)(vt + (size_t)(b * 256 + d0 + dr) * 4096 + t0 + tc8 * 8) = *(const uint4*)&Tv[dr][tc8 * 8];
  }
}

// ---------------------------------------------------------------------------
// mbuild: Mt[b][j][d2][d1] = sum_t V[t][d2] * K~[t][d1]  (= M^T), bf16 out.
// ---------------------------------------------------------------------------
__global__ __launch_bounds__(256) void mbuild_kernel(const unsigned short* __restrict__ kt,
                                                     const unsigned short* __restrict__ vt,
                                                     unsigned short* __restrict__ mt) {
  const int tid = threadIdx.x;
  const int lane = tid & 63;
  const int wid = tid >> 6;
  const int l31 = lane & 31, lh = lane >> 5;
  const int jc = blockIdx.x;
  const int quad = blockIdx.y;
  const int b = blockIdx.z;
  const int d2w = ((quad >> 1) * 2 + (wid >> 1)) * 64;
  const int d1w = ((quad & 1) * 2 + (wid & 1)) * 64;
  const size_t tb = (size_t)jc * 256;

  f32x16 acc[2][2];
#pragma unroll
  for (int i = 0; i < 2; ++i)
#pragma unroll
    for (int j = 0; j < 2; ++j) acc[i][j] = 0.0f;

#pragma unroll 2
  for (int dc = 0; dc < 16; ++dc) {
    const int ko = dc * 32 + lh * 16;
    bf16x8 a[2], bb[2];
#pragma unroll
    for (int i = 0; i < 2; ++i) {
      a[i]  = *(const bf16x8*)((const char*)vt + ((size_t)(b * 256 + d2w + i * 32 + l31) * 4096 + tb) * 2 + ko);
      bb[i] = *(const bf16x8*)((const char*)kt + ((size_t)(b * 256 + d1w + i * 32 + l31) * 4096 + tb) * 2 + ko);
    }
#pragma unroll
    for (int i = 0; i < 2; ++i)
#pragma unroll
      for (int j = 0; j < 2; ++j)
        acc[i][j] = __builtin_amdgcn_mfma_f32_32x32x16_bf16(a[i], bb[j], acc[i][j], 0, 0, 0);
  }
  unsigned short* dst = mt + ((size_t)(b * 16 + jc) << 16);
#pragma unroll
  for (int i = 0; i < 2; ++i)
#pragma unroll
    for (int j = 0; j < 2; ++j)
#pragma unroll
      for (int reg = 0; reg < 16; ++reg) {
        int row = d2w + i * 32 + (reg & 3) + 8 * (reg >> 2) + 4 * lh;
        int col = d1w + j * 32 + l31;
        dst[row * 256 + col] = f2bf(acc[i][j][reg]);
      }
}

// ---------------------------------------------------------------------------
// scan: S_j = GC*(S_{j-1} + M_{j-1}), in place to slot j-1 (bf16).
// ---------------------------------------------------------------------------
__global__ __launch_bounds__(256) void scan_kernel(unsigned short* __restrict__ mt) {
  const int e0 = (blockIdx.x * 256 + threadIdx.x) * 4;
  const int b = blockIdx.y;
  unsigned short* base = mt + ((size_t)b << 20);
  float s0 = 0.f, s1 = 0.f, s2 = 0.f, s3 = 0.f;
  for (int j = 1; j < 16; ++j) {
    unsigned short* p = base + ((size_t)(j - 1) << 16) + e0;
    uint2 mv = *(const uint2*)p;
    s0 = GC * (s0 + bf2f(mv.x & 0xffffu));
    s1 = GC * (s1 + bf2f(mv.x >> 16));
    s2 = GC * (s2 + bf2f(mv.y & 0xffffu));
    s3 = GC * (s3 + bf2f(mv.y >> 16));
    uint2 w;
    w.x = f2bf(s0) | ((unsigned int)f2bf(s1) << 16);
    w.y = f2bf(s2) | ((unsigned int)f2bf(s3) << 16);
    *(uint2*)p = w;
  }
}

// ---------------------------------------------------------------------------
// retc: out = Q~ @ S_j (cross) + causal-intra(Q~ K~^T) @ V
// Grid (128 st32, 2 dh, 4 b) = 1024 blocks; 4 waves (tw) split cross-dc and
// intra t-tiles (parity). Two-stage LDS combine (32 KB) -> 4 blocks/CU.
// ---------------------------------------------------------------------------
__global__ __launch_bounds__(256, 2) void retc_kernel(const unsigned short* __restrict__ qkv,
                                                      const unsigned short* __restrict__ vt,
                                                      const unsigned short* __restrict__ mt,
                                                      float* __restrict__ out) {
  __shared__ float cmb[2][32][128];
  const int tid = threadIdx.x;
  const int lane = tid & 63;
  const int tw = tid >> 6;          // 0..3
  const int l31 = lane & 31, lh = lane >> 5;
  const int st = blockIdx.x;        // 32-row s-tile
  const int dh = blockIdx.y;        // d-half (128 cols)
  const int b = blockIdx.z;
  const int j = st >> 3;
  const int base = st & ~7;
  const int s0 = st * 32;
  const int d0 = dh * 128;

  // hoist Q~ fragments (rows s0+l31, full D)
  bf16x8 qf[16];
  {
    const char* qrow = (const char*)qkv + ((size_t)b * Sn + s0 + l31) * 1536;
#pragma unroll
    for (int dc = 0; dc < 16; ++dc)
      qf[dc] = *(const bf16x8*)(qrow + dc * 32 + lh * 16);
  }

  f32x16 acc[4];
#pragma unroll
  for (int i = 0; i < 4; ++i) acc[i] = 0.0f;

  // cross: acc += Q~ @ S_j, dc-chunks split across tw
  if (j > 0) {
    const char* Sj = (const char*)mt + ((size_t)(b * 16 + j - 1) << 17);
#pragma unroll
    for (int dcl = 0; dcl < 4; ++dcl) {
      const int dc = tw * 4 + dcl;
#pragma unroll
      for (int g = 0; g < 4; ++g) {
        const int d2 = d0 + g * 32 + l31;
        bf16x8 sbf = *(const bf16x8*)(Sj + (size_t)d2 * 512 + dc * 32 + lh * 16);
        acc[g] = __builtin_amdgcn_mfma_f32_32x32x16_bf16(qf[dc], sbf, acc[g], 0, 0, 0);
      }
    }
  }

  // intra-chunk causal, t-tiles split across tw by parity
  const int sg = s0 + l31;
  const int ksw = (l31 & 7) << 4;
  for (int tt = base; tt <= st; ++tt) {
    if (((tt - base) & 3) != tw) continue;
    const bool msk = (tt == st);
    const int t0 = tt * 32;

    f32x16 sacc = 0.0f;
    const char* krow = (const char*)qkv + ((size_t)b * Sn + t0 + l31) * 1536 + 512;
    __builtin_amdgcn_s_setprio(1);
#pragma unroll
    for (int dc = 0; dc < 16; ++dc) {
      bf16x8 kf = *(const bf16x8*)(krow + ((dc * 32 + lh * 16) ^ ksw));
      sacc = __builtin_amdgcn_mfma_f32_32x32x16_bf16(kf, qf[dc], sacc, 0, 0, 0);
    }
    __builtin_amdgcn_s_setprio(0);

    unsigned int P[8];
#pragma unroll
    for (int k = 0; k < 8; ++k) {
      const int r0 = 2 * k;
      float f0 = sacc[r0], f1 = sacc[r0 + 1];
      if (msk) {
        const int tg0 = t0 + (r0 & 3) + 8 * (r0 >> 2) + 4 * lh;
        f0 = (sg - tg0 >= 0) ? f0 : 0.0f;
        f1 = (sg - tg0 - 1 >= 0) ? f1 : 0.0f;
      }
      unsigned int pk;
      asm("v_cvt_pk_bf16_f32 %0, %1, %2" : "=v"(pk) : "v"(f0), "v"(f1));
      P[k] = pk;
    }
    asm volatile("v_permlane32_swap_b32 %0, %1" : "+v"(P[0]), "+v"(P[2]));
    asm volatile("v_permlane32_swap_b32 %0, %1" : "+v"(P[1]), "+v"(P[3]));
    asm volatile("v_permlane32_swap_b32 %0, %1" : "+v"(P[4]), "+v"(P[6]));
    asm volatile("v_permlane32_swap_b32 %0, %1" : "+v"(P[5]), "+v"(P[7]));

    __builtin_amdgcn_s_setprio(1);
#pragma unroll
    for (int kc = 0; kc < 2; ++kc) {
      uint4 pw;
      pw.x = P[kc * 4 + 0]; pw.y = P[kc * 4 + 1];
      pw.z = P[kc * 4 + 2]; pw.w = P[kc * 4 + 3];
      bf16x8 pf = *(const bf16x8*)&pw;
#pragma unroll
      for (int g = 0; g < 4; ++g) {
        const int d = d0 + g * 32 + l31;
        bf16x8 vf = *(const bf16x8*)((const char*)vt +
            ((size_t)(b * 256 + d) * 4096 + t0) * 2 + kc * 32 + lh * 16);
        acc[g] = __builtin_amdgcn_mfma_f32_32x32x16_bf16(pf, vf, acc[g], 0, 0, 0);
      }
    }
    __builtin_amdgcn_s_setprio(0);
  }

  // two-stage combine across the 4 tw waves (cmb = 32 KB)
  if (tw >= 2) {  // tw2 -> cmb[0], tw3 -> cmb[1]
#pragma unroll
    for (int g = 0; g < 4; ++g)
#pragma unroll
      for (int reg = 0; reg < 16; ++reg) {
        int sl = (reg & 3) + 8 * (reg >> 2) + 4 * lh;
        cmb[tw - 2][sl][g * 32 + l31] = acc[g][reg];
      }
  }
  __syncthreads();
  if (tw < 2) {   // tw0 += cmb[0], tw1 += cmb[1]
#pragma unroll
    for (int g = 0; g < 4; ++g)
#pragma unroll
      for (int reg = 0; reg < 16; ++reg) {
        int sl = (reg & 3) + 8 * (reg >> 2) + 4 * lh;
        acc[g][reg] += cmb[tw][sl][g * 32 + l31];
      }
  }
  __syncthreads();
  if (tw == 1) {  // tw1 -> cmb[0]
#pragma unroll
    for (int g = 0; g < 4; ++g)
#pragma unroll
      for (int reg = 0; reg < 16; ++reg) {
        int sl = (reg & 3) + 8 * (reg >> 2) + 4 * lh;
        cmb[0][sl][g * 32 + l31] = acc[g][reg];
      }
  }
  __syncthreads();
  if (tw == 0) {  // final add + store
#pragma unroll
    for (int g = 0; g < 4; ++g)
#pragma unroll
      for (int reg = 0; reg < 16; ++reg) {
        int sl = (reg & 3) + 8 * (reg >> 2) + 4 * lh;
        int c = g * 32 + l31;
        out[((size_t)(b * Sn + s0 + sl)) * 256 + d0 + c] = acc[g][reg] + cmb[0][sl][c];
      }
  }
}

// ---------------------------------------------------------------------------
extern "C" void kernel_launch(void* const* d_in, const int* in_sizes, int n_in,
                              void* d_out, int out_size, void* d_ws, size_t ws_size,
                              hipStream_t stream) {
  (void)in_sizes; (void)n_in; (void)out_size;
  const float* x  = (const float*)d_in[0];
  const float* wq = (const float*)d_in[1];
  const float* wk = (const float*)d_in[2];
  const float* wv = (const float*)d_in[3];
  float* out = (float*)d_out;
  char* ws = (char*)d_ws;

  unsigned short* qkv = (unsigned short*)(ws);              // 25,165,824 B
  unsigned short* vt  = (unsigned short*)(ws + 25165824);   //  8,388,608 B
  unsigned short* kt  = (unsigned short*)(ws + 33554432);   //  8,388,608 B
  unsigned short* mt  = (unsigned short*)(ws + 41943040);   //  8,388,608 B

  const size_t NEED_BIG = 95420416;  // qkv + xb(67.1MB, aliases kt/vt/mt) + wt
  if (ws_size >= NEED_BIG) {
    unsigned short* xb = (unsigned short*)(ws + 25165824);  // dead after proj2
    unsigned short* wt = (unsigned short*)(ws + 92274688);
    xbf_kernel<<<8192, 256, 0, stream>>>(x, xb);
    wt_build<<<dim3(32, 12), 256, 0, stream>>>(wq, wk, wv, wt);
    proj2_kernel<<<dim3(128, 6), 256, 0, stream>>>(xb, wt, qkv);
  } else {
    unsigned short* wt = (unsigned short*)(ws + 41943040);  // alias mt
    wt_build<<<dim3(32, 12), 256, 0, stream>>>(wq, wk, wv, wt);
    proj_kernel<<<dim3(128, 6), 256, 0, stream>>>(x, wt, qkv);
  }
  xpos_kernel<<<2048, 256, 0, stream>>>(qkv);
  kvt_build<<<dim3(64, 4, 4), 256, 0, stream>>>(qkv, kt, vt);
  mbuild_kernel<<<dim3(16, 4, 4), 256, 0, stream>>>(kt, vt, mt);
  scan_kernel<<<dim3(64, 4), 256, 0, stream>>>(mt);
  retc_kernel<<<dim3(128, 2, 4), 256, 0, stream>>>(qkv, vt, mt, out);
}